// Round 13
// baseline (159.232 us; speedup 1.0000x reference)
//
#include <hip/hip_runtime.h>
#include <hip/hip_bf16.h>

// (B,H,S,D) = (2,8,4096,64)
#define S_   4096
#define D_   64
#define BH_  16
#define QW   64        // q rows per wave (two 32-col MFMA blocks)
#define QBLK 256       // q rows per block (4 waves)
#define KVB  128       // keys per staged tile (two 64-key halves per barrier)
#define NCH  2         // kv chunks (grid z)

typedef __attribute__((ext_vector_type(8)))  short short8_t;   // 8 bf16 (MFMA A/B frag)
typedef __attribute__((ext_vector_type(16))) float f32x16;     // 32x32 MFMA C/D frag
#define QSCALE 0.18033688011112042f   /* (1/8)*log2(e): scores in log2 domain */

__device__ __forceinline__ unsigned short f2bf(float f) {
  unsigned u = __float_as_uint(f);
  u += 0x7fffu + ((u >> 16) & 1u);   // RTNE
  return (unsigned short)(u >> 16);
}

__device__ __forceinline__ void glds16(const unsigned short* g, unsigned short* l) {
  __builtin_amdgcn_global_load_lds(
      (const __attribute__((address_space(1))) unsigned int*)g,
      (__attribute__((address_space(3))) unsigned int*)l, 16, 0, 0);
}

// o[i] = bf16((a[i]+b[i])*scale)  -- used for Q only
__global__ void addcvt2_kernel(const float* __restrict__ a, const float* __restrict__ b,
                               unsigned short* __restrict__ o, float scale, int n) {
  int i = (blockIdx.x * blockDim.x + threadIdx.x) * 4;
  if (i >= n) return;
  float4 x = *(const float4*)(a + i);
  float4 y = *(const float4*)(b + i);
  ushort4 r;
  r.x = f2bf((x.x + y.x) * scale); r.y = f2bf((x.y + y.y) * scale);
  r.z = f2bf((x.z + y.z) * scale); r.w = f2bf((x.w + y.w) * scale);
  *(ushort4*)(o + i) = r;
}

// per batch: prefix-scan mask, emit compacted key indices + count
__global__ void compact_kernel(const int* __restrict__ mask, int* __restrict__ idx,
                               int* __restrict__ cnt) {
  __shared__ int ps[256];
  int b = blockIdx.x, tid = threadIdx.x;
  const int* mb = mask + (size_t)b * S_;
  int m[16], c = 0;
  int base = tid * 16;
#pragma unroll
  for (int i = 0; i < 16; ++i) { m[i] = mb[base + i]; c += (m[i] != 0); }
  ps[tid] = c;
  __syncthreads();
  for (int off = 1; off < 256; off <<= 1) {   // Hillis-Steele inclusive scan
    int add = (tid >= off) ? ps[tid - off] : 0;
    __syncthreads();
    ps[tid] += add;
    __syncthreads();
  }
  int pos = ps[tid] - c;   // exclusive prefix
#pragma unroll
  for (int i = 0; i < 16; ++i) if (m[i]) idx[(size_t)b * S_ + pos++] = base + i;
  if (tid == 255) cnt[b] = ps[255];
}

// fused gather: khat[bh][j][d] (row-major) and vt[bh][d][j] (transposed); zeros j >= C
__global__ void kvgather_kernel(const float* __restrict__ ka, const float* __restrict__ ks,
                                const float* __restrict__ va, const float* __restrict__ vs,
                                const int* __restrict__ idx, const int* __restrict__ cnt,
                                unsigned short* __restrict__ khat,
                                unsigned short* __restrict__ vt) {
  __shared__ __align__(16) unsigned short t[D_][72];
  int bh = blockIdx.y, b = bh >> 3;
  int s0 = blockIdx.x * 64;
  int C = cnt[b];
  int tid = threadIdx.x;
  int row16 = tid >> 4;
  int col4  = (tid & 15) * 4;
#pragma unroll
  for (int p = 0; p < 4; ++p) {
    int srow = p * 16 + row16;
    int j = s0 + srow;
    float4 xv = {0, 0, 0, 0}, yv = {0, 0, 0, 0};
    float4 xk = {0, 0, 0, 0}, yk = {0, 0, 0, 0};
    if (j < C) {
      int src = idx[(size_t)b * S_ + j];
      size_t off = ((size_t)bh * S_ + src) * D_ + col4;
      xv = *(const float4*)(va + off);
      yv = *(const float4*)(vs + off);
      xk = *(const float4*)(ka + off);
      yk = *(const float4*)(ks + off);
    }
    t[col4 + 0][srow] = f2bf(xv.x + yv.x);
    t[col4 + 1][srow] = f2bf(xv.y + yv.y);
    t[col4 + 2][srow] = f2bf(xv.z + yv.z);
    t[col4 + 3][srow] = f2bf(xv.w + yv.w);
    ushort4 rk;
    rk.x = f2bf(xk.x + yk.x); rk.y = f2bf(xk.y + yk.y);
    rk.z = f2bf(xk.z + yk.z); rk.w = f2bf(xk.w + yk.w);
    *(ushort4*)(khat + ((size_t)bh * S_ + j) * D_ + col4) = rk;
  }
  __syncthreads();
#pragma unroll
  for (int r = 0; r < 2; ++r) {
    int e = (r * 256 + tid) * 8;
    int d = e >> 6, sc = e & 63;
    short8_t v = *(const short8_t*)&t[d][sc];
    *(short8_t*)(vt + ((size_t)bh * D_ + d) * S_ + s0 + sc) = v;
  }
}

// Flash attention over compacted keys. Swapped-QK^T 32x32x16, two q-blocks/wave,
// 128-key tiles processed as two 64-key halves per barrier interval. (R11-verified body.)
__global__ __launch_bounds__(256, 3) void attn_kernel(
    const unsigned short* __restrict__ Qb, const unsigned short* __restrict__ Kb,
    const unsigned short* __restrict__ Vt, const int* __restrict__ cnt,
    float* __restrict__ out, float* __restrict__ Opar, float2* __restrict__ Ml) {
  __shared__ __align__(16) unsigned short lK[2][KVB * 64];   // [key][d]
  __shared__ __align__(16) unsigned short lV[2][64 * KVB];   // [d][key]

  const int tid  = threadIdx.x;
  const int wave = tid >> 6;
  const int lane = tid & 63;
  const int l31  = lane & 31;
  const int h5   = lane >> 5;
  const int rsw  = l31 & 7;
  const int bh   = blockIdx.y;
  const int ch   = blockIdx.z;
  const int qrow0 = blockIdx.x * QBLK + wave * QW + l31;   // q-block 0; +32 for q-block 1
  const int b    = bh >> 3;
  const int C    = cnt[b];
  const int NTt  = (C + KVB - 1) / KVB;          // total 128-key tiles
  const int tpc  = (NTt + NCH - 1) / NCH;        // tiles per chunk
  const int ts   = ch * tpc;
  const int te   = (ts + tpc < NTt) ? (ts + tpc) : NTt;

  // Q fragments (B-operand): qf[qb][t4] = Q[qrow0 + 32*qb][t4*16 + h5*8 .. +7]
  short8_t qf[2][4];
#pragma unroll
  for (int qb = 0; qb < 2; ++qb) {
    const unsigned short* qp = Qb + ((size_t)bh * S_ + qrow0 + 32 * qb) * D_ + h5 * 8;
#pragma unroll
    for (int t4 = 0; t4 < 4; ++t4) qf[qb][t4] = *(const short8_t*)(qp + t4 * 16);
  }

  const unsigned short* gk0 = Kb + (size_t)bh * S_ * D_;
  const unsigned short* gv0 = Vt + (size_t)bh * D_ * S_;

  // staging geometry (1024 16B-chunks per tile per tensor; 4 per thread):
  // K [128 key rows][8 groups]: row=c>>3, src group = (c&7)^(row&7)   [m173 pattern]
  // V [64 d rows][16 groups]:   row=c>>4, src group = (g&8)|((g&7)^(row&7))
  int srcK[4], srcV[4], ldsB[4];
#pragma unroll
  for (int r2 = 0; r2 < 4; ++r2) {
    int c = r2 * 256 + tid;
    int rowK = c >> 3, gK = (c & 7) ^ (rowK & 7);
    srcK[r2] = rowK * 64 + gK * 8;
    int rowV = c >> 4, gg = c & 15;
    int swg = (gg & 8) | ((gg & 7) ^ (rowV & 7));
    srcV[r2] = rowV * S_ + swg * 8;
    ldsB[r2] = r2 * 2048 + wave * 512;   // wave-uniform base (elems); HW adds lane*16B
  }

  f32x16 acc0[2], acc1[2];
  float mrow[2], lrow[2];
#pragma unroll
  for (int qb = 0; qb < 2; ++qb) {
    acc0[qb] = (f32x16)(0.0f); acc1[qb] = (f32x16)(0.0f);
    mrow[qb] = -1e30f; lrow[qb] = 0.0f;
  }

  if (ts < te) {
    // stage tile ts into buf0
#pragma unroll
    for (int r2 = 0; r2 < 4; ++r2) {
      glds16(gk0 + (size_t)ts * KVB * D_ + srcK[r2], &lK[0][ldsB[r2]]);
      glds16(gv0 + ts * KVB + srcV[r2], &lV[0][ldsB[r2]]);
    }
    __syncthreads();

    for (int t = ts; t < te; ++t) {
      const int cur = (t - ts) & 1;
      if (t + 1 < te) {   // prefetch next tile into other buffer
#pragma unroll
        for (int r2 = 0; r2 < 4; ++r2) {
          glds16(gk0 + (size_t)(t + 1) * KVB * D_ + srcK[r2], &lK[cur ^ 1][ldsB[r2]]);
          glds16(gv0 + (t + 1) * KVB + srcV[r2], &lV[cur ^ 1][ldsB[r2]]);
        }
      }

#pragma unroll
      for (int h = 0; h < 2; ++h) {   // two 64-key halves of the staged tile
        // ---- S^T = K Q^T : K-frags shared across both q-blocks
        f32x16 sv0[2], sv1[2];
#pragma unroll
        for (int qb = 0; qb < 2; ++qb) { sv0[qb] = (f32x16)(0.0f); sv1[qb] = (f32x16)(0.0f); }
        __builtin_amdgcn_s_setprio(1);
#pragma unroll
        for (int t4 = 0; t4 < 4; ++t4) {
          int g = ((2 * t4 + h5) ^ rsw) * 8;
          short8_t kf0 = *(const short8_t*)&lK[cur][(h * 64 + l31) * 64 + g];
          short8_t kf1 = *(const short8_t*)&lK[cur][(h * 64 + 32 + l31) * 64 + g];
          sv0[0] = __builtin_amdgcn_mfma_f32_32x32x16_bf16(kf0, qf[0][t4], sv0[0], 0, 0, 0);
          sv0[1] = __builtin_amdgcn_mfma_f32_32x32x16_bf16(kf0, qf[1][t4], sv0[1], 0, 0, 0);
          sv1[0] = __builtin_amdgcn_mfma_f32_32x32x16_bf16(kf1, qf[0][t4], sv1[0], 0, 0, 0);
          sv1[1] = __builtin_amdgcn_mfma_f32_32x32x16_bf16(kf1, qf[1][t4], sv1[1], 0, 0, 0);
        }
        __builtin_amdgcn_s_setprio(0);

        // ---- tail: pad keys (key >= C) -> -1e9 (reg->key mapping, no memory)
        if (t == NTt - 1) {
          int kvb = t * KVB + h * 64;
#pragma unroll
          for (int i = 0; i < 16; ++i) {
            int key = kvb + (i & 3) + 8 * (i >> 2) + 4 * h5;
#pragma unroll
            for (int qb = 0; qb < 2; ++qb) {
              if (key >= C) sv0[qb][i] = -1e9f;
              if (key + 32 >= C) sv1[qb][i] = -1e9f;
            }
          }
        }

        // ---- online softmax per q-block (in-register, log2 domain)
        unsigned int pkw[2][16];
#pragma unroll
        for (int qb = 0; qb < 2; ++qb) {
          float tmx[8];
#pragma unroll
          for (int i = 0; i < 8; ++i)
            tmx[i] = fmaxf(fmaxf(sv0[qb][i], sv0[qb][i + 8]),
                           fmaxf(sv1[qb][i], sv1[qb][i + 8]));
#pragma unroll
          for (int i = 0; i < 4; ++i) tmx[i] = fmaxf(tmx[i], tmx[i + 4]);
          float tm = fmaxf(fmaxf(tmx[0], tmx[1]), fmaxf(tmx[2], tmx[3]));
          tm = fmaxf(tm, __shfl_xor(tm, 32));

          if (__any(tm > mrow[qb] + 8.0f)) {   // defer-max (T13)
            float mnew = fmaxf(mrow[qb], tm);
            float sc = __builtin_amdgcn_exp2f(mrow[qb] - mnew);
            mrow[qb] = mnew;
            lrow[qb] *= sc;
#pragma unroll
            for (int i = 0; i < 16; ++i) { acc0[qb][i] *= sc; acc1[qb][i] *= sc; }
          }

          float m = mrow[qb];
          float t0 = 0.f, t1 = 0.f, t2 = 0.f, t3 = 0.f;
#pragma unroll
          for (int i = 0; i < 16; i += 4) {
            sv0[qb][i + 0] = __builtin_amdgcn_exp2f(sv0[qb][i + 0] - m); t0 += sv0[qb][i + 0];
            sv0[qb][i + 1] = __builtin_amdgcn_exp2f(sv0[qb][i + 1] - m); t1 += sv0[qb][i + 1];
            sv0[qb][i + 2] = __builtin_amdgcn_exp2f(sv0[qb][i + 2] - m); t2 += sv0[qb][i + 2];
            sv0[qb][i + 3] = __builtin_amdgcn_exp2f(sv0[qb][i + 3] - m); t3 += sv0[qb][i + 3];
            sv1[qb][i + 0] = __builtin_amdgcn_exp2f(sv1[qb][i + 0] - m); t0 += sv1[qb][i + 0];
            sv1[qb][i + 1] = __builtin_amdgcn_exp2f(sv1[qb][i + 1] - m); t1 += sv1[qb][i + 1];
            sv1[qb][i + 2] = __builtin_amdgcn_exp2f(sv1[qb][i + 2] - m); t2 += sv1[qb][i + 2];
            sv1[qb][i + 3] = __builtin_amdgcn_exp2f(sv1[qb][i + 3] - m); t3 += sv1[qb][i + 3];
          }
          float tsum = (t0 + t1) + (t2 + t3);
          tsum += __shfl_xor(tsum, 32);
          lrow[qb] += tsum;

          // pack: pkw[qb][n*8+rg*2+c] = keys n*32 + rg*8 + 4*h5 + 2c, +1
#pragma unroll
          for (int rg = 0; rg < 4; ++rg) {
            __hip_bfloat162 a0 = __float22bfloat162_rn({sv0[qb][rg * 4 + 0], sv0[qb][rg * 4 + 1]});
            __hip_bfloat162 a1 = __float22bfloat162_rn({sv0[qb][rg * 4 + 2], sv0[qb][rg * 4 + 3]});
            __hip_bfloat162 b0 = __float22bfloat162_rn({sv1[qb][rg * 4 + 0], sv1[qb][rg * 4 + 1]});
            __hip_bfloat162 b1 = __float22bfloat162_rn({sv1[qb][rg * 4 + 2], sv1[qb][rg * 4 + 3]});
            pkw[qb][rg * 2 + 0] = *(unsigned int*)&a0;
            pkw[qb][rg * 2 + 1] = *(unsigned int*)&a1;
            pkw[qb][8 + rg * 2 + 0] = *(unsigned int*)&b0;
            pkw[qb][8 + rg * 2 + 1] = *(unsigned int*)&b1;
          }
        }

        // ---- O^T += V^T P : half-swap redistribution via shfl (R4-verified mapping)
        __builtin_amdgcn_s_setprio(1);
#pragma unroll
        for (int kt = 0; kt < 4; ++kt) {
          const int n = kt >> 1, k1 = kt & 1;
          int gcol = ((h * 8) | ((2 * kt + h5) ^ rsw)) * 8;
          short8_t vf0 = *(const short8_t*)&lV[cur][l31 * KVB + gcol];
          short8_t vf1 = *(const short8_t*)&lV[cur][(32 + l31) * KVB + gcol];
#pragma unroll
          for (int qb = 0; qb < 2; ++qb) {
            unsigned int sA = pkw[qb][n * 8 + (2 * k1 + h5) * 2 + 0];
            unsigned int sB = pkw[qb][n * 8 + (2 * k1 + h5) * 2 + 1];
            unsigned int xA = pkw[qb][n * 8 + (2 * k1 + (h5 ^ 1)) * 2 + 0];
            unsigned int xB = pkw[qb][n * 8 + (2 * k1 + (h5 ^ 1)) * 2 + 1];
            unsigned int pA = (unsigned int)__shfl_xor((int)xA, 32);
            unsigned int pB = (unsigned int)__shfl_xor((int)xB, 32);
            union { unsigned int u[4]; short8_t v; } bb;
            bb.u[0] = h5 ? pA : sA;
            bb.u[1] = h5 ? pB : sB;
            bb.u[2] = h5 ? sA : pA;
            bb.u[3] = h5 ? sB : pB;
            acc0[qb] = __builtin_amdgcn_mfma_f32_32x32x16_bf16(vf0, bb.v, acc0[qb], 0, 0, 0);
            acc1[qb] = __builtin_amdgcn_mfma_f32_32x32x16_bf16(vf1, bb.v, acc1[qb], 0, 0, 0);
          }
        }
        __builtin_amdgcn_s_setprio(0);
      }

      __syncthreads();   // drains prefetch + separates buffers
    }
  }

  // ---- epilogue: unnormalized partial O + (m,l) stats, per q-block
  float* Op = (ch == 0) ? out : Opar;
#pragma unroll
  for (int qb = 0; qb < 2; ++qb) {
    float* op = Op + ((size_t)bh * S_ + qrow0 + 32 * qb) * D_;
#pragma unroll
    for (int rg = 0; rg < 4; ++rg) {
      float4 o0, o1;
      o0.x = acc0[qb][rg * 4 + 0]; o0.y = acc0[qb][rg * 4 + 1];
      o0.z = acc0[qb][rg * 4 + 2]; o0.w = acc0[qb][rg * 4 + 3];
      o1.x = acc1[qb][rg * 4 + 0]; o1.y = acc1[qb][rg * 4 + 1];
      o1.z = acc1[qb][rg * 4 + 2]; o1.w = acc1[qb][rg * 4 + 3];
      *(float4*)(op + rg * 8 + h5 * 4) = o0;
      *(float4*)(op + 32 + rg * 8 + h5 * 4) = o1;
    }
    if (h5 == 0) {
      float2 st; st.x = mrow[qb]; st.y = lrow[qb];
      Ml[(size_t)ch * (BH_ * S_) + (size_t)bh * S_ + qrow0 + 32 * qb] = st;
    }
  }
}

// merge 2 KV-chunk partials: out = (O0*w0 + O1*w1) / (l0*w0 + l1*w1), wi = 2^(mi - M)
__global__ void combine_kernel(const float* __restrict__ O1, const float2* __restrict__ Ml,
                               float* __restrict__ out) {
  int gid = blockIdx.x * 256 + threadIdx.x;   // (row, 16-d quarter)
  int row = gid >> 2, qd = (gid & 3) * 16;
  float2 a = Ml[row];                    // chunk 0
  float2 b = Ml[BH_ * S_ + row];         // chunk 1
  float M = fmaxf(a.x, b.x);
  float w0 = exp2f(a.x - M), w1 = exp2f(b.x - M);
  float inv = 1.0f / (a.y * w0 + b.y * w1);
  w0 *= inv; w1 *= inv;
  const float4* p0 = (const float4*)(out + (size_t)row * D_ + qd);  // chunk0 partial in out
  const float4* p1 = (const float4*)(O1 + (size_t)row * D_ + qd);
  float4* po = (float4*)(out + (size_t)row * D_ + qd);
#pragma unroll
  for (int i = 0; i < 4; ++i) {
    float4 x = p0[i], y = p1[i];
    float4 r;
    r.x = x.x * w0 + y.x * w1; r.y = x.y * w0 + y.y * w1;
    r.z = x.z * w0 + y.z * w1; r.w = x.w * w0 + y.w * w1;
    po[i] = r;
  }
}

extern "C" void kernel_launch(void* const* d_in, const int* in_sizes, int n_in,
                              void* d_out, int out_size, void* d_ws, size_t ws_size,
                              hipStream_t stream) {
  const float* q_a = (const float*)d_in[0];
  const float* k_a = (const float*)d_in[1];
  const float* v_a = (const float*)d_in[2];
  const float* q_s = (const float*)d_in[3];
  const float* k_s = (const float*)d_in[4];
  const float* v_s = (const float*)d_in[5];
  const int*   mask = (const int*)d_in[6];
  float* out = (float*)d_out;
  (void)in_sizes; (void)n_in; (void)out_size; (void)ws_size;

  const int N = BH_ * S_ * D_;   // 4,194,304
  unsigned short* qb   = (unsigned short*)d_ws;
  unsigned short* khat = qb + N;
  unsigned short* vt   = khat + N;
  int*  idx  = (int*)(vt + N);           // 2*S_ ints
  int*  cnt  = idx + 2 * S_;             // 4 ints (padded for 16B alignment)
  float* O1  = (float*)(cnt + 4);        // N floats (chunk-1 partial)
  float2* ml = (float2*)(O1 + N);        // NCH * BH_*S_ float2

  compact_kernel<<<2, 256, 0, stream>>>(mask, idx, cnt);
  addcvt2_kernel<<<N / 1024, 256, 0, stream>>>(q_a, q_s, qb, QSCALE, N);
  {
    dim3 g(S_ / 64, BH_);
    kvgather_kernel<<<g, 256, 0, stream>>>(k_a, k_s, v_a, v_s, idx, cnt, khat, vt);
  }
  {
    dim3 g(S_ / QBLK, BH_, NCH);
    attn_kernel<<<g, 256, 0, stream>>>(qb, khat, vt, cnt, out, O1, ml);
  }
  combine_kernel<<<(BH_ * S_ * 4) / 256, 256, 0, stream>>>(O1, ml, out);
}

// Round 14
// 126.344 us; speedup vs baseline: 1.2603x; 1.2603x over previous
//
#include <hip/hip_runtime.h>
#include <hip/hip_bf16.h>

// (B,H,S,D) = (2,8,4096,64)
#define S_   4096
#define D_   64
#define BH_  16
#define QW   64        // q rows per wave (two 32-col MFMA blocks)
#define QBLK 256       // q rows per block (4 waves)
#define KVB  128       // keys per staged tile (two 64-key halves per barrier)
#define NCH  2         // kv chunks (grid z)

typedef __attribute__((ext_vector_type(8)))  short short8_t;   // 8 bf16 (MFMA A/B frag)
typedef __attribute__((ext_vector_type(16))) float f32x16;     // 32x32 MFMA C/D frag
#define QSCALE 0.18033688011112042f   /* (1/8)*log2(e): scores in log2 domain */

__device__ __forceinline__ unsigned short f2bf(float f) {
  unsigned u = __float_as_uint(f);
  u += 0x7fffu + ((u >> 16) & 1u);   // RTNE
  return (unsigned short)(u >> 16);
}

__device__ __forceinline__ void glds16(const unsigned short* g, unsigned short* l) {
  __builtin_amdgcn_global_load_lds(
      (const __attribute__((address_space(1))) unsigned int*)g,
      (__attribute__((address_space(3))) unsigned int*)l, 16, 0, 0);
}

// o[i] = bf16((a[i]+b[i])*scale)  -- used for Q only
__global__ void addcvt2_kernel(const float* __restrict__ a, const float* __restrict__ b,
                               unsigned short* __restrict__ o, float scale, int n) {
  int i = (blockIdx.x * blockDim.x + threadIdx.x) * 4;
  if (i >= n) return;
  float4 x = *(const float4*)(a + i);
  float4 y = *(const float4*)(b + i);
  ushort4 r;
  r.x = f2bf((x.x + y.x) * scale); r.y = f2bf((x.y + y.y) * scale);
  r.z = f2bf((x.z + y.z) * scale); r.w = f2bf((x.w + y.w) * scale);
  *(ushort4*)(o + i) = r;
}

// per batch: prefix-scan mask, emit compacted key indices + count
__global__ void compact_kernel(const int* __restrict__ mask, int* __restrict__ idx,
                               int* __restrict__ cnt) {
  __shared__ int ps[256];
  int b = blockIdx.x, tid = threadIdx.x;
  const int* mb = mask + (size_t)b * S_;
  int m[16], c = 0;
  int base = tid * 16;
#pragma unroll
  for (int i = 0; i < 16; ++i) { m[i] = mb[base + i]; c += (m[i] != 0); }
  ps[tid] = c;
  __syncthreads();
  for (int off = 1; off < 256; off <<= 1) {   // Hillis-Steele inclusive scan
    int add = (tid >= off) ? ps[tid - off] : 0;
    __syncthreads();
    ps[tid] += add;
    __syncthreads();
  }
  int pos = ps[tid] - c;   // exclusive prefix
#pragma unroll
  for (int i = 0; i < 16; ++i) if (m[i]) idx[(size_t)b * S_ + pos++] = base + i;
  if (tid == 255) cnt[b] = ps[255];
}

// fused gather: khat[bh][j][d] (row-major) and vt[bh][d][j] (transposed); zeros j >= C
__global__ void kvgather_kernel(const float* __restrict__ ka, const float* __restrict__ ks,
                                const float* __restrict__ va, const float* __restrict__ vs,
                                const int* __restrict__ idx, const int* __restrict__ cnt,
                                unsigned short* __restrict__ khat,
                                unsigned short* __restrict__ vt) {
  __shared__ __align__(16) unsigned short t[D_][72];
  int bh = blockIdx.y, b = bh >> 3;
  int s0 = blockIdx.x * 64;
  int C = cnt[b];
  int tid = threadIdx.x;
  int row16 = tid >> 4;
  int col4  = (tid & 15) * 4;
#pragma unroll
  for (int p = 0; p < 4; ++p) {
    int srow = p * 16 + row16;
    int j = s0 + srow;
    float4 xv = {0, 0, 0, 0}, yv = {0, 0, 0, 0};
    float4 xk = {0, 0, 0, 0}, yk = {0, 0, 0, 0};
    if (j < C) {
      int src = idx[(size_t)b * S_ + j];
      size_t off = ((size_t)bh * S_ + src) * D_ + col4;
      xv = *(const float4*)(va + off);
      yv = *(const float4*)(vs + off);
      xk = *(const float4*)(ka + off);
      yk = *(const float4*)(ks + off);
    }
    t[col4 + 0][srow] = f2bf(xv.x + yv.x);
    t[col4 + 1][srow] = f2bf(xv.y + yv.y);
    t[col4 + 2][srow] = f2bf(xv.z + yv.z);
    t[col4 + 3][srow] = f2bf(xv.w + yv.w);
    ushort4 rk;
    rk.x = f2bf(xk.x + yk.x); rk.y = f2bf(xk.y + yk.y);
    rk.z = f2bf(xk.z + yk.z); rk.w = f2bf(xk.w + yk.w);
    *(ushort4*)(khat + ((size_t)bh * S_ + j) * D_ + col4) = rk;
  }
  __syncthreads();
#pragma unroll
  for (int r = 0; r < 2; ++r) {
    int e = (r * 256 + tid) * 8;
    int d = e >> 6, sc = e & 63;
    short8_t v = *(const short8_t*)&t[d][sc];
    *(short8_t*)(vt + ((size_t)bh * D_ + d) * S_ + s0 + sc) = v;
  }
}

// Flash attention over compacted keys. Swapped-QK^T 32x32x16, two q-blocks/wave,
// 128-key tiles as two 64-key halves. R11-verified math; counted-vmcnt pipeline (T4):
// prefetch loads stay in flight across raw s_barriers, no per-tile vmcnt(0) drain.
__global__ __launch_bounds__(256, 2) void attn_kernel(
    const unsigned short* __restrict__ Qb, const unsigned short* __restrict__ Kb,
    const unsigned short* __restrict__ Vt, const int* __restrict__ cnt,
    float* __restrict__ out, float* __restrict__ Opar, float2* __restrict__ Ml) {
  __shared__ __align__(16) unsigned short lK[2][KVB * 64];   // [key][d]
  __shared__ __align__(16) unsigned short lV[2][64 * KVB];   // [d][key]

  const int tid  = threadIdx.x;
  const int wave = tid >> 6;
  const int lane = tid & 63;
  const int l31  = lane & 31;
  const int h5   = lane >> 5;
  const int rsw  = l31 & 7;
  const int bh   = blockIdx.y;
  const int ch   = blockIdx.z;
  const int qrow0 = blockIdx.x * QBLK + wave * QW + l31;   // q-block 0; +32 for q-block 1
  const int b    = bh >> 3;
  const int C    = cnt[b];
  const int NTt  = (C + KVB - 1) / KVB;          // total 128-key tiles
  const int tpc  = (NTt + NCH - 1) / NCH;        // tiles per chunk
  const int ts   = ch * tpc;
  const int te   = (ts + tpc < NTt) ? (ts + tpc) : NTt;

  // Q fragments (B-operand): qf[qb][t4] = Q[qrow0 + 32*qb][t4*16 + h5*8 .. +7]
  short8_t qf[2][4];
#pragma unroll
  for (int qb = 0; qb < 2; ++qb) {
    const unsigned short* qp = Qb + ((size_t)bh * S_ + qrow0 + 32 * qb) * D_ + h5 * 8;
#pragma unroll
    for (int t4 = 0; t4 < 4; ++t4) qf[qb][t4] = *(const short8_t*)(qp + t4 * 16);
  }

  const unsigned short* gk0 = Kb + (size_t)bh * S_ * D_;
  const unsigned short* gv0 = Vt + (size_t)bh * D_ * S_;

  // staging geometry (1024 16B-chunks per tile per tensor; 4 per thread):
  // K [128 key rows][8 groups]: row=c>>3, src group = (c&7)^(row&7)   [m173 pattern]
  // V [64 d rows][16 groups]:   row=c>>4, src group = (g&8)|((g&7)^(row&7))
  int srcK[4], srcV[4], ldsB[4];
#pragma unroll
  for (int r2 = 0; r2 < 4; ++r2) {
    int c = r2 * 256 + tid;
    int rowK = c >> 3, gK = (c & 7) ^ (rowK & 7);
    srcK[r2] = rowK * 64 + gK * 8;
    int rowV = c >> 4, gg = c & 15;
    int swg = (gg & 8) | ((gg & 7) ^ (rowV & 7));
    srcV[r2] = rowV * S_ + swg * 8;
    ldsB[r2] = r2 * 2048 + wave * 512;   // wave-uniform base (elems); HW adds lane*16B
  }

  f32x16 acc0[2], acc1[2];
  float mrow[2], lrow[2];
#pragma unroll
  for (int qb = 0; qb < 2; ++qb) {
    acc0[qb] = (f32x16)(0.0f); acc1[qb] = (f32x16)(0.0f);
    mrow[qb] = -1e30f; lrow[qb] = 0.0f;
  }

  if (ts < te) {
    // prologue: issue tile-ts loads into buf0 (8 per wave); no drain here
#pragma unroll
    for (int r2 = 0; r2 < 4; ++r2) {
      glds16(gk0 + (size_t)ts * KVB * D_ + srcK[r2], &lK[0][ldsB[r2]]);
      glds16(gv0 + ts * KVB + srcV[r2], &lV[0][ldsB[r2]]);
    }

    for (int t = ts; t < te; ++t) {
      const int cur = (t - ts) & 1;
      if (t + 1 < te) {
        // issue next-tile loads (8) THEN wait for the previous 8 only (counted vmcnt)
#pragma unroll
        for (int r2 = 0; r2 < 4; ++r2) {
          glds16(gk0 + (size_t)(t + 1) * KVB * D_ + srcK[r2], &lK[cur ^ 1][ldsB[r2]]);
          glds16(gv0 + (t + 1) * KVB + srcV[r2], &lV[cur ^ 1][ldsB[r2]]);
        }
        asm volatile("s_waitcnt vmcnt(8)" ::: "memory");
      } else {
        asm volatile("s_waitcnt vmcnt(0)" ::: "memory");
      }
      __builtin_amdgcn_s_barrier();          // tile t visible to all waves (no drain)
      __builtin_amdgcn_sched_barrier(0);     // pin ds_reads below the barrier

#pragma unroll
      for (int h = 0; h < 2; ++h) {   // two 64-key halves of the staged tile
        // ---- S^T = K Q^T : K-frags shared across both q-blocks
        f32x16 sv0[2], sv1[2];
#pragma unroll
        for (int qb = 0; qb < 2; ++qb) { sv0[qb] = (f32x16)(0.0f); sv1[qb] = (f32x16)(0.0f); }
        __builtin_amdgcn_s_setprio(1);
#pragma unroll
        for (int t4 = 0; t4 < 4; ++t4) {
          int g = ((2 * t4 + h5) ^ rsw) * 8;
          short8_t kf0 = *(const short8_t*)&lK[cur][(h * 64 + l31) * 64 + g];
          short8_t kf1 = *(const short8_t*)&lK[cur][(h * 64 + 32 + l31) * 64 + g];
          sv0[0] = __builtin_amdgcn_mfma_f32_32x32x16_bf16(kf0, qf[0][t4], sv0[0], 0, 0, 0);
          sv0[1] = __builtin_amdgcn_mfma_f32_32x32x16_bf16(kf0, qf[1][t4], sv0[1], 0, 0, 0);
          sv1[0] = __builtin_amdgcn_mfma_f32_32x32x16_bf16(kf1, qf[0][t4], sv1[0], 0, 0, 0);
          sv1[1] = __builtin_amdgcn_mfma_f32_32x32x16_bf16(kf1, qf[1][t4], sv1[1], 0, 0, 0);
        }
        __builtin_amdgcn_s_setprio(0);

        // ---- tail: pad keys (key >= C) -> -1e9 (reg->key mapping, no memory)
        if (t == NTt - 1) {
          int kvb = t * KVB + h * 64;
#pragma unroll
          for (int i = 0; i < 16; ++i) {
            int key = kvb + (i & 3) + 8 * (i >> 2) + 4 * h5;
#pragma unroll
            for (int qb = 0; qb < 2; ++qb) {
              if (key >= C) sv0[qb][i] = -1e9f;
              if (key + 32 >= C) sv1[qb][i] = -1e9f;
            }
          }
        }

        // ---- online softmax per q-block (in-register, log2 domain)
        unsigned int pkw[2][16];
#pragma unroll
        for (int qb = 0; qb < 2; ++qb) {
          float tmx[8];
#pragma unroll
          for (int i = 0; i < 8; ++i)
            tmx[i] = fmaxf(fmaxf(sv0[qb][i], sv0[qb][i + 8]),
                           fmaxf(sv1[qb][i], sv1[qb][i + 8]));
#pragma unroll
          for (int i = 0; i < 4; ++i) tmx[i] = fmaxf(tmx[i], tmx[i + 4]);
          float tm = fmaxf(fmaxf(tmx[0], tmx[1]), fmaxf(tmx[2], tmx[3]));
          tm = fmaxf(tm, __shfl_xor(tm, 32));

          if (__any(tm > mrow[qb] + 8.0f)) {   // defer-max (T13)
            float mnew = fmaxf(mrow[qb], tm);
            float sc = __builtin_amdgcn_exp2f(mrow[qb] - mnew);
            mrow[qb] = mnew;
            lrow[qb] *= sc;
#pragma unroll
            for (int i = 0; i < 16; ++i) { acc0[qb][i] *= sc; acc1[qb][i] *= sc; }
          }

          float m = mrow[qb];
          float t0 = 0.f, t1 = 0.f, t2 = 0.f, t3 = 0.f;
#pragma unroll
          for (int i = 0; i < 16; i += 4) {
            sv0[qb][i + 0] = __builtin_amdgcn_exp2f(sv0[qb][i + 0] - m); t0 += sv0[qb][i + 0];
            sv0[qb][i + 1] = __builtin_amdgcn_exp2f(sv0[qb][i + 1] - m); t1 += sv0[qb][i + 1];
            sv0[qb][i + 2] = __builtin_amdgcn_exp2f(sv0[qb][i + 2] - m); t2 += sv0[qb][i + 2];
            sv0[qb][i + 3] = __builtin_amdgcn_exp2f(sv0[qb][i + 3] - m); t3 += sv0[qb][i + 3];
            sv1[qb][i + 0] = __builtin_amdgcn_exp2f(sv1[qb][i + 0] - m); t0 += sv1[qb][i + 0];
            sv1[qb][i + 1] = __builtin_amdgcn_exp2f(sv1[qb][i + 1] - m); t1 += sv1[qb][i + 1];
            sv1[qb][i + 2] = __builtin_amdgcn_exp2f(sv1[qb][i + 2] - m); t2 += sv1[qb][i + 2];
            sv1[qb][i + 3] = __builtin_amdgcn_exp2f(sv1[qb][i + 3] - m); t3 += sv1[qb][i + 3];
          }
          float tsum = (t0 + t1) + (t2 + t3);
          tsum += __shfl_xor(tsum, 32);
          lrow[qb] += tsum;

          // pack: pkw[qb][n*8+rg*2+c] = keys n*32 + rg*8 + 4*h5 + 2c, +1
#pragma unroll
          for (int rg = 0; rg < 4; ++rg) {
            __hip_bfloat162 a0 = __float22bfloat162_rn({sv0[qb][rg * 4 + 0], sv0[qb][rg * 4 + 1]});
            __hip_bfloat162 a1 = __float22bfloat162_rn({sv0[qb][rg * 4 + 2], sv0[qb][rg * 4 + 3]});
            __hip_bfloat162 b0 = __float22bfloat162_rn({sv1[qb][rg * 4 + 0], sv1[qb][rg * 4 + 1]});
            __hip_bfloat162 b1 = __float22bfloat162_rn({sv1[qb][rg * 4 + 2], sv1[qb][rg * 4 + 3]});
            pkw[qb][rg * 2 + 0] = *(unsigned int*)&a0;
            pkw[qb][rg * 2 + 1] = *(unsigned int*)&a1;
            pkw[qb][8 + rg * 2 + 0] = *(unsigned int*)&b0;
            pkw[qb][8 + rg * 2 + 1] = *(unsigned int*)&b1;
          }
        }

        // ---- O^T += V^T P : half-swap redistribution via shfl (R4-verified mapping)
        __builtin_amdgcn_s_setprio(1);
#pragma unroll
        for (int kt = 0; kt < 4; ++kt) {
          const int n = kt >> 1, k1 = kt & 1;
          int gcol = ((h * 8) | ((2 * kt + h5) ^ rsw)) * 8;
          short8_t vf0 = *(const short8_t*)&lV[cur][l31 * KVB + gcol];
          short8_t vf1 = *(const short8_t*)&lV[cur][(32 + l31) * KVB + gcol];
#pragma unroll
          for (int qb = 0; qb < 2; ++qb) {
            unsigned int sA = pkw[qb][n * 8 + (2 * k1 + h5) * 2 + 0];
            unsigned int sB = pkw[qb][n * 8 + (2 * k1 + h5) * 2 + 1];
            unsigned int xA = pkw[qb][n * 8 + (2 * k1 + (h5 ^ 1)) * 2 + 0];
            unsigned int xB = pkw[qb][n * 8 + (2 * k1 + (h5 ^ 1)) * 2 + 1];
            unsigned int pA = (unsigned int)__shfl_xor((int)xA, 32);
            unsigned int pB = (unsigned int)__shfl_xor((int)xB, 32);
            union { unsigned int u[4]; short8_t v; } bb;
            bb.u[0] = h5 ? pA : sA;
            bb.u[1] = h5 ? pB : sB;
            bb.u[2] = h5 ? sA : pA;
            bb.u[3] = h5 ? sB : pB;
            acc0[qb] = __builtin_amdgcn_mfma_f32_32x32x16_bf16(vf0, bb.v, acc0[qb], 0, 0, 0);
            acc1[qb] = __builtin_amdgcn_mfma_f32_32x32x16_bf16(vf1, bb.v, acc1[qb], 0, 0, 0);
          }
        }
        __builtin_amdgcn_s_setprio(0);
      }

      __builtin_amdgcn_sched_barrier(0);
      __builtin_amdgcn_s_barrier();   // all waves done reading buf[cur] (no vmcnt drain);
                                      // next iter's glds (which overwrite it) issue after this
    }
  }

  // ---- epilogue: unnormalized partial O + (m,l) stats, per q-block
  float* Op = (ch == 0) ? out : Opar;
#pragma unroll
  for (int qb = 0; qb < 2; ++qb) {
    float* op = Op + ((size_t)bh * S_ + qrow0 + 32 * qb) * D_;
#pragma unroll
    for (int rg = 0; rg < 4; ++rg) {
      float4 o0, o1;
      o0.x = acc0[qb][rg * 4 + 0]; o0.y = acc0[qb][rg * 4 + 1];
      o0.z = acc0[qb][rg * 4 + 2]; o0.w = acc0[qb][rg * 4 + 3];
      o1.x = acc1[qb][rg * 4 + 0]; o1.y = acc1[qb][rg * 4 + 1];
      o1.z = acc1[qb][rg * 4 + 2]; o1.w = acc1[qb][rg * 4 + 3];
      *(float4*)(op + rg * 8 + h5 * 4) = o0;
      *(float4*)(op + 32 + rg * 8 + h5 * 4) = o1;
    }
    if (h5 == 0) {
      float2 st; st.x = mrow[qb]; st.y = lrow[qb];
      Ml[(size_t)ch * (BH_ * S_) + (size_t)bh * S_ + qrow0 + 32 * qb] = st;
    }
  }
}

// merge 2 KV-chunk partials: out = (O0*w0 + O1*w1) / (l0*w0 + l1*w1), wi = 2^(mi - M)
__global__ void combine_kernel(const float* __restrict__ O1, const float2* __restrict__ Ml,
                               float* __restrict__ out) {
  int gid = blockIdx.x * 256 + threadIdx.x;   // (row, 16-d quarter)
  int row = gid >> 2, qd = (gid & 3) * 16;
  float2 a = Ml[row];                    // chunk 0
  float2 b = Ml[BH_ * S_ + row];         // chunk 1
  float M = fmaxf(a.x, b.x);
  float w0 = exp2f(a.x - M), w1 = exp2f(b.x - M);
  float inv = 1.0f / (a.y * w0 + b.y * w1);
  w0 *= inv; w1 *= inv;
  const float4* p0 = (const float4*)(out + (size_t)row * D_ + qd);  // chunk0 partial in out
  const float4* p1 = (const float4*)(O1 + (size_t)row * D_ + qd);
  float4* po = (float4*)(out + (size_t)row * D_ + qd);
#pragma unroll
  for (int i = 0; i < 4; ++i) {
    float4 x = p0[i], y = p1[i];
    float4 r;
    r.x = x.x * w0 + y.x * w1; r.y = x.y * w0 + y.y * w1;
    r.z = x.z * w0 + y.z * w1; r.w = x.w * w0 + y.w * w1;
    po[i] = r;
  }
}

extern "C" void kernel_launch(void* const* d_in, const int* in_sizes, int n_in,
                              void* d_out, int out_size, void* d_ws, size_t ws_size,
                              hipStream_t stream) {
  const float* q_a = (const float*)d_in[0];
  const float* k_a = (const float*)d_in[1];
  const float* v_a = (const float*)d_in[2];
  const float* q_s = (const float*)d_in[3];
  const float* k_s = (const float*)d_in[4];
  const float* v_s = (const float*)d_in[5];
  const int*   mask = (const int*)d_in[6];
  float* out = (float*)d_out;
  (void)in_sizes; (void)n_in; (void)out_size; (void)ws_size;

  const int N = BH_ * S_ * D_;   // 4,194,304
  unsigned short* qb   = (unsigned short*)d_ws;
  unsigned short* khat = qb + N;
  unsigned short* vt   = khat + N;
  int*  idx  = (int*)(vt + N);           // 2*S_ ints
  int*  cnt  = idx + 2 * S_;             // 4 ints (padded for 16B alignment)
  float* O1  = (float*)(cnt + 4);        // N floats (chunk-1 partial)
  float2* ml = (float2*)(O1 + N);        // NCH * BH_*S_ float2

  compact_kernel<<<2, 256, 0, stream>>>(mask, idx, cnt);
  addcvt2_kernel<<<N / 1024, 256, 0, stream>>>(q_a, q_s, qb, QSCALE, N);
  {
    dim3 g(S_ / 64, BH_);
    kvgather_kernel<<<g, 256, 0, stream>>>(k_a, k_s, v_a, v_s, idx, cnt, khat, vt);
  }
  {
    dim3 g(S_ / QBLK, BH_, NCH);
    attn_kernel<<<g, 256, 0, stream>>>(qb, khat, vt, cnt, out, O1, ml);
  }
  combine_kernel<<<(BH_ * S_ * 4) / 256, 256, 0, stream>>>(O1, ml, out);
}

// Round 16
// 123.985 us; speedup vs baseline: 1.2843x; 1.0190x over previous
//
#include <hip/hip_runtime.h>
#include <hip/hip_bf16.h>

// (B,H,S,D) = (2,8,4096,64)
#define S_   4096
#define D_   64
#define BH_  16
#define QW   64        // q rows per wave (two 32-col MFMA blocks)
#define QBLK 256       // q rows per block (4 waves)
#define KVB  128       // keys per staged tile (two 64-key halves per barrier)
#define NCH  2         // kv chunks (grid z)

typedef __attribute__((ext_vector_type(8)))  short short8_t;   // 8 bf16 (MFMA A/B frag)
typedef __attribute__((ext_vector_type(16))) float f32x16;     // 32x32 MFMA C/D frag
#define QSCALE 0.18033688011112042f   /* (1/8)*log2(e): scores in log2 domain */

__device__ __forceinline__ unsigned short f2bf(float f) {
  unsigned u = __float_as_uint(f);
  u += 0x7fffu + ((u >> 16) & 1u);   // RTNE
  return (unsigned short)(u >> 16);
}

__device__ __forceinline__ void glds16(const unsigned short* g, unsigned short* l) {
  __builtin_amdgcn_global_load_lds(
      (const __attribute__((address_space(1))) unsigned int*)g,
      (__attribute__((address_space(3))) unsigned int*)l, 16, 0, 0);
}

// fused: per-batch mask scan (compact) + K/V gather + bf16 convert + V transpose.
// khat[bh][j][d] row-major, vt[bh][d][j] transposed; zeros for j >= C.
__global__ void kvgather_kernel(const float* __restrict__ ka, const float* __restrict__ ks,
                                const float* __restrict__ va, const float* __restrict__ vs,
                                const int* __restrict__ mask, int* __restrict__ cnt,
                                unsigned short* __restrict__ khat,
                                unsigned short* __restrict__ vt) {
  __shared__ int ps[256];
  __shared__ int srcLds[64];
  __shared__ __align__(16) unsigned short t[D_][72];
  const int bh = blockIdx.y, b = bh >> 3;
  const int s0 = blockIdx.x * 64;
  const int tid = threadIdx.x;

  // ---- scan mask[b][*]: rank of each set bit; collect ranks in [s0, s0+64)
  const int* mb = mask + (size_t)b * S_;
  int m[16], c = 0;
  const int base = tid * 16;
#pragma unroll
  for (int i = 0; i < 16; ++i) { m[i] = mb[base + i]; c += (m[i] != 0); }
  ps[tid] = c;
  __syncthreads();
  for (int off = 1; off < 256; off <<= 1) {   // Hillis-Steele inclusive scan
    int add = (tid >= off) ? ps[tid - off] : 0;
    __syncthreads();
    ps[tid] += add;
    __syncthreads();
  }
  const int C = ps[255];
  int pos = ps[tid] - c;   // exclusive prefix
#pragma unroll
  for (int i = 0; i < 16; ++i) {
    if (m[i]) {
      int r = pos++;
      if (r >= s0 && r < s0 + 64) srcLds[r - s0] = base + i;
    }
  }
  if (tid == 0 && blockIdx.x == 0 && (bh & 7) == 0) cnt[b] = C;
  __syncthreads();

  // ---- gather 64 output keys, convert, stage V for transpose
  const int row16 = tid >> 4;
  const int col4  = (tid & 15) * 4;
#pragma unroll
  for (int p = 0; p < 4; ++p) {
    int srow = p * 16 + row16;
    int j = s0 + srow;
    float4 xv = {0, 0, 0, 0}, yv = {0, 0, 0, 0};
    float4 xk = {0, 0, 0, 0}, yk = {0, 0, 0, 0};
    if (j < C) {
      int src = srcLds[srow];
      size_t off = ((size_t)bh * S_ + src) * D_ + col4;
      xv = *(const float4*)(va + off);
      yv = *(const float4*)(vs + off);
      xk = *(const float4*)(ka + off);
      yk = *(const float4*)(ks + off);
    }
    t[col4 + 0][srow] = f2bf(xv.x + yv.x);
    t[col4 + 1][srow] = f2bf(xv.y + yv.y);
    t[col4 + 2][srow] = f2bf(xv.z + yv.z);
    t[col4 + 3][srow] = f2bf(xv.w + yv.w);
    ushort4 rk;
    rk.x = f2bf(xk.x + yk.x); rk.y = f2bf(xk.y + yk.y);
    rk.z = f2bf(xk.z + yk.z); rk.w = f2bf(xk.w + yk.w);
    *(ushort4*)(khat + ((size_t)bh * S_ + j) * D_ + col4) = rk;
  }
  __syncthreads();
#pragma unroll
  for (int r = 0; r < 2; ++r) {
    int e = (r * 256 + tid) * 8;
    int d = e >> 6, sc = e & 63;
    short8_t v = *(const short8_t*)&t[d][sc];
    *(short8_t*)(vt + ((size_t)bh * D_ + d) * S_ + s0 + sc) = v;
  }
}

// Flash attention over compacted keys. Swapped-QK^T 32x32x16, two q-blocks/wave,
// 128-key tiles as two 64-key halves. R11-verified math; counted-vmcnt pipeline;
// Q add+scale+bf16 fused into the prologue (reads q_a/q_s fp32 directly).
// Cross-lane exchange: __shfl_xor ONLY (inline permlane asm banned: R3/R5/R15 failures).
__global__ __launch_bounds__(256, 2) void attn_kernel(
    const float* __restrict__ Qa, const float* __restrict__ Qs,
    const unsigned short* __restrict__ Kb, const unsigned short* __restrict__ Vt,
    const int* __restrict__ cnt,
    float* __restrict__ out, float* __restrict__ Opar, float2* __restrict__ Ml) {
  __shared__ __align__(16) unsigned short lK[2][KVB * 64];   // [key][d]
  __shared__ __align__(16) unsigned short lV[2][64 * KVB];   // [d][key]

  const int tid  = threadIdx.x;
  const int wave = tid >> 6;
  const int lane = tid & 63;
  const int l31  = lane & 31;
  const int h5   = lane >> 5;
  const int rsw  = l31 & 7;
  const int bh   = blockIdx.y;
  const int ch   = blockIdx.z;
  const int qrow0 = blockIdx.x * QBLK + wave * QW + l31;   // q-block 0; +32 for q-block 1
  const int b    = bh >> 3;
  const int C    = cnt[b];
  const int NTt  = (C + KVB - 1) / KVB;          // total 128-key tiles
  const int tpc  = (NTt + NCH - 1) / NCH;        // tiles per chunk
  const int ts   = ch * tpc;
  const int te   = (ts + tpc < NTt) ? (ts + tpc) : NTt;

  // Q fragments built on the fly: qf[qb][t4] = bf16((q_a+q_s)*QSCALE)[row][t4*16+h5*8..+7]
  short8_t qf[2][4];
#pragma unroll
  for (int qb = 0; qb < 2; ++qb) {
    size_t off = ((size_t)bh * S_ + qrow0 + 32 * qb) * D_ + h5 * 8;
    const float* qa = Qa + off;
    const float* qs = Qs + off;
#pragma unroll
    for (int t4 = 0; t4 < 4; ++t4) {
      float4 a0 = *(const float4*)(qa + t4 * 16);
      float4 a1 = *(const float4*)(qa + t4 * 16 + 4);
      float4 s0 = *(const float4*)(qs + t4 * 16);
      float4 s1 = *(const float4*)(qs + t4 * 16 + 4);
      union { unsigned short u[8]; short8_t v; } qq;
      qq.u[0] = f2bf((a0.x + s0.x) * QSCALE); qq.u[1] = f2bf((a0.y + s0.y) * QSCALE);
      qq.u[2] = f2bf((a0.z + s0.z) * QSCALE); qq.u[3] = f2bf((a0.w + s0.w) * QSCALE);
      qq.u[4] = f2bf((a1.x + s1.x) * QSCALE); qq.u[5] = f2bf((a1.y + s1.y) * QSCALE);
      qq.u[6] = f2bf((a1.z + s1.z) * QSCALE); qq.u[7] = f2bf((a1.w + s1.w) * QSCALE);
      qf[qb][t4] = qq.v;
    }
  }

  const unsigned short* gk0 = Kb + (size_t)bh * S_ * D_;
  const unsigned short* gv0 = Vt + (size_t)bh * D_ * S_;

  // staging geometry (1024 16B-chunks per tile per tensor; 4 per thread):
  // K [128 key rows][8 groups]: row=c>>3, src group = (c&7)^(row&7)   [m173 pattern]
  // V [64 d rows][16 groups]:   row=c>>4, src group = (g&8)|((g&7)^(row&7))
  int srcK[4], srcV[4], ldsB[4];
#pragma unroll
  for (int r2 = 0; r2 < 4; ++r2) {
    int c = r2 * 256 + tid;
    int rowK = c >> 3, gK = (c & 7) ^ (rowK & 7);
    srcK[r2] = rowK * 64 + gK * 8;
    int rowV = c >> 4, gg = c & 15;
    int swg = (gg & 8) | ((gg & 7) ^ (rowV & 7));
    srcV[r2] = rowV * S_ + swg * 8;
    ldsB[r2] = r2 * 2048 + wave * 512;   // wave-uniform base (elems); HW adds lane*16B
  }

  f32x16 acc0[2], acc1[2];
  float mrow[2], lrow[2];
#pragma unroll
  for (int qb = 0; qb < 2; ++qb) {
    acc0[qb] = (f32x16)(0.0f); acc1[qb] = (f32x16)(0.0f);
    mrow[qb] = -1e30f; lrow[qb] = 0.0f;
  }

  if (ts < te) {
    // prologue: issue tile-ts loads into buf0 (8 per wave); no drain here
#pragma unroll
    for (int r2 = 0; r2 < 4; ++r2) {
      glds16(gk0 + (size_t)ts * KVB * D_ + srcK[r2], &lK[0][ldsB[r2]]);
      glds16(gv0 + ts * KVB + srcV[r2], &lV[0][ldsB[r2]]);
    }

    for (int t = ts; t < te; ++t) {
      const int cur = (t - ts) & 1;
      if (t + 1 < te) {
        // issue next-tile loads (8) THEN wait for the previous 8 only (counted vmcnt)
#pragma unroll
        for (int r2 = 0; r2 < 4; ++r2) {
          glds16(gk0 + (size_t)(t + 1) * KVB * D_ + srcK[r2], &lK[cur ^ 1][ldsB[r2]]);
          glds16(gv0 + (t + 1) * KVB + srcV[r2], &lV[cur ^ 1][ldsB[r2]]);
        }
        asm volatile("s_waitcnt vmcnt(8)" ::: "memory");
      } else {
        asm volatile("s_waitcnt vmcnt(0)" ::: "memory");
      }
      __builtin_amdgcn_s_barrier();          // tile t visible to all waves (no drain)
      __builtin_amdgcn_sched_barrier(0);     // pin ds_reads below the barrier

#pragma unroll
      for (int h = 0; h < 2; ++h) {   // two 64-key halves of the staged tile
        // ---- S^T = K Q^T : K-frags shared across both q-blocks
        f32x16 sv0[2], sv1[2];
#pragma unroll
        for (int qb = 0; qb < 2; ++qb) { sv0[qb] = (f32x16)(0.0f); sv1[qb] = (f32x16)(0.0f); }
        __builtin_amdgcn_s_setprio(1);
#pragma unroll
        for (int t4 = 0; t4 < 4; ++t4) {
          int g = ((2 * t4 + h5) ^ rsw) * 8;
          short8_t kf0 = *(const short8_t*)&lK[cur][(h * 64 + l31) * 64 + g];
          short8_t kf1 = *(const short8_t*)&lK[cur][(h * 64 + 32 + l31) * 64 + g];
          sv0[0] = __builtin_amdgcn_mfma_f32_32x32x16_bf16(kf0, qf[0][t4], sv0[0], 0, 0, 0);
          sv0[1] = __builtin_amdgcn_mfma_f32_32x32x16_bf16(kf0, qf[1][t4], sv0[1], 0, 0, 0);
          sv1[0] = __builtin_amdgcn_mfma_f32_32x32x16_bf16(kf1, qf[0][t4], sv1[0], 0, 0, 0);
          sv1[1] = __builtin_amdgcn_mfma_f32_32x32x16_bf16(kf1, qf[1][t4], sv1[1], 0, 0, 0);
        }
        __builtin_amdgcn_s_setprio(0);

        // ---- tail: pad keys (key >= C) -> -1e9 (reg->key mapping, no memory)
        if (t == NTt - 1) {
          int kvb = t * KVB + h * 64;
#pragma unroll
          for (int i = 0; i < 16; ++i) {
            int key = kvb + (i & 3) + 8 * (i >> 2) + 4 * h5;
#pragma unroll
            for (int qb = 0; qb < 2; ++qb) {
              if (key >= C) sv0[qb][i] = -1e9f;
              if (key + 32 >= C) sv1[qb][i] = -1e9f;
            }
          }
        }

        // ---- online softmax per q-block (in-register, log2 domain)
        unsigned int pkw[2][16];
#pragma unroll
        for (int qb = 0; qb < 2; ++qb) {
          float tmx[8];
#pragma unroll
          for (int i = 0; i < 8; ++i)
            tmx[i] = fmaxf(fmaxf(sv0[qb][i], sv0[qb][i + 8]),
                           fmaxf(sv1[qb][i], sv1[qb][i + 8]));
#pragma unroll
          for (int i = 0; i < 4; ++i) tmx[i] = fmaxf(tmx[i], tmx[i + 4]);
          float tm = fmaxf(fmaxf(tmx[0], tmx[1]), fmaxf(tmx[2], tmx[3]));
          tm = fmaxf(tm, __shfl_xor(tm, 32));

          if (__any(tm > mrow[qb] + 8.0f)) {   // defer-max (T13)
            float mnew = fmaxf(mrow[qb], tm);
            float sc = __builtin_amdgcn_exp2f(mrow[qb] - mnew);
            mrow[qb] = mnew;
            lrow[qb] *= sc;
#pragma unroll
            for (int i = 0; i < 16; ++i) { acc0[qb][i] *= sc; acc1[qb][i] *= sc; }
          }

          float m = mrow[qb];
          float t0 = 0.f, t1 = 0.f, t2 = 0.f, t3 = 0.f;
#pragma unroll
          for (int i = 0; i < 16; i += 4) {
            sv0[qb][i + 0] = __builtin_amdgcn_exp2f(sv0[qb][i + 0] - m); t0 += sv0[qb][i + 0];
            sv0[qb][i + 1] = __builtin_amdgcn_exp2f(sv0[qb][i + 1] - m); t1 += sv0[qb][i + 1];
            sv0[qb][i + 2] = __builtin_amdgcn_exp2f(sv0[qb][i + 2] - m); t2 += sv0[qb][i + 2];
            sv0[qb][i + 3] = __builtin_amdgcn_exp2f(sv0[qb][i + 3] - m); t3 += sv0[qb][i + 3];
            sv1[qb][i + 0] = __builtin_amdgcn_exp2f(sv1[qb][i + 0] - m); t0 += sv1[qb][i + 0];
            sv1[qb][i + 1] = __builtin_amdgcn_exp2f(sv1[qb][i + 1] - m); t1 += sv1[qb][i + 1];
            sv1[qb][i + 2] = __builtin_amdgcn_exp2f(sv1[qb][i + 2] - m); t2 += sv1[qb][i + 2];
            sv1[qb][i + 3] = __builtin_amdgcn_exp2f(sv1[qb][i + 3] - m); t3 += sv1[qb][i + 3];
          }
          float tsum = (t0 + t1) + (t2 + t3);
          tsum += __shfl_xor(tsum, 32);
          lrow[qb] += tsum;

          // pack: pkw[qb][n*8+rg*2+c] = keys n*32 + rg*8 + 4*h5 + 2c, +1
#pragma unroll
          for (int rg = 0; rg < 4; ++rg) {
            __hip_bfloat162 a0 = __float22bfloat162_rn({sv0[qb][rg * 4 + 0], sv0[qb][rg * 4 + 1]});
            __hip_bfloat162 a1 = __float22bfloat162_rn({sv0[qb][rg * 4 + 2], sv0[qb][rg * 4 + 3]});
            __hip_bfloat162 b0 = __float22bfloat162_rn({sv1[qb][rg * 4 + 0], sv1[qb][rg * 4 + 1]});
            __hip_bfloat162 b1 = __float22bfloat162_rn({sv1[qb][rg * 4 + 2], sv1[qb][rg * 4 + 3]});
            pkw[qb][rg * 2 + 0] = *(unsigned int*)&a0;
            pkw[qb][rg * 2 + 1] = *(unsigned int*)&a1;
            pkw[qb][8 + rg * 2 + 0] = *(unsigned int*)&b0;
            pkw[qb][8 + rg * 2 + 1] = *(unsigned int*)&b1;
          }
        }

        // ---- O^T += V^T P : half-swap redistribution via shfl (R4-verified mapping)
        __builtin_amdgcn_s_setprio(1);
#pragma unroll
        for (int kt = 0; kt < 4; ++kt) {
          const int n = kt >> 1, k1 = kt & 1;
          int gcol = ((h * 8) | ((2 * kt + h5) ^ rsw)) * 8;
          short8_t vf0 = *(const short8_t*)&lV[cur][l31 * KVB + gcol];
          short8_t vf1 = *(const short8_t*)&lV[cur][(32 + l31) * KVB + gcol];
#pragma unroll
          for (int qb = 0; qb < 2; ++qb) {
            unsigned int sA = pkw[qb][n * 8 + (2 * k1 + h5) * 2 + 0];
            unsigned int sB = pkw[qb][n * 8 + (2 * k1 + h5) * 2 + 1];
            unsigned int xA = pkw[qb][n * 8 + (2 * k1 + (h5 ^ 1)) * 2 + 0];
            unsigned int xB = pkw[qb][n * 8 + (2 * k1 + (h5 ^ 1)) * 2 + 1];
            unsigned int pA = (unsigned int)__shfl_xor((int)xA, 32);
            unsigned int pB = (unsigned int)__shfl_xor((int)xB, 32);
            union { unsigned int u[4]; short8_t v; } bb;
            bb.u[0] = h5 ? pA : sA;
            bb.u[1] = h5 ? pB : sB;
            bb.u[2] = h5 ? sA : pA;
            bb.u[3] = h5 ? sB : pB;
            acc0[qb] = __builtin_amdgcn_mfma_f32_32x32x16_bf16(vf0, bb.v, acc0[qb], 0, 0, 0);
            acc1[qb] = __builtin_amdgcn_mfma_f32_32x32x16_bf16(vf1, bb.v, acc1[qb], 0, 0, 0);
          }
        }
        __builtin_amdgcn_s_setprio(0);
      }

      __builtin_amdgcn_sched_barrier(0);
      __builtin_amdgcn_s_barrier();   // all waves done reading buf[cur] before next glds
    }
  }

  // ---- epilogue: unnormalized partial O + (m,l) stats, per q-block
  float* Op = (ch == 0) ? out : Opar;
#pragma unroll
  for (int qb = 0; qb < 2; ++qb) {
    float* op = Op + ((size_t)bh * S_ + qrow0 + 32 * qb) * D_;
#pragma unroll
    for (int rg = 0; rg < 4; ++rg) {
      float4 o0, o1;
      o0.x = acc0[qb][rg * 4 + 0]; o0.y = acc0[qb][rg * 4 + 1];
      o0.z = acc0[qb][rg * 4 + 2]; o0.w = acc0[qb][rg * 4 + 3];
      o1.x = acc1[qb][rg * 4 + 0]; o1.y = acc1[qb][rg * 4 + 1];
      o1.z = acc1[qb][rg * 4 + 2]; o1.w = acc1[qb][rg * 4 + 3];
      *(float4*)(op + rg * 8 + h5 * 4) = o0;
      *(float4*)(op + 32 + rg * 8 + h5 * 4) = o1;
    }
    if (h5 == 0) {
      float2 st; st.x = mrow[qb]; st.y = lrow[qb];
      Ml[(size_t)ch * (BH_ * S_) + (size_t)bh * S_ + qrow0 + 32 * qb] = st;
    }
  }
}

// merge 2 KV-chunk partials: out = (O0*w0 + O1*w1) / (l0*w0 + l1*w1), wi = 2^(mi - M)
__global__ void combine_kernel(const float* __restrict__ O1, const float2* __restrict__ Ml,
                               float* __restrict__ out) {
  int gid = blockIdx.x * 256 + threadIdx.x;   // (row, 16-d quarter)
  int row = gid >> 2, qd = (gid & 3) * 16;
  float2 a = Ml[row];                    // chunk 0
  float2 b = Ml[BH_ * S_ + row];         // chunk 1
  float M = fmaxf(a.x, b.x);
  float w0 = exp2f(a.x - M), w1 = exp2f(b.x - M);
  float inv = 1.0f / (a.y * w0 + b.y * w1);
  w0 *= inv; w1 *= inv;
  const float4* p0 = (const float4*)(out + (size_t)row * D_ + qd);  // chunk0 partial in out
  const float4* p1 = (const float4*)(O1 + (size_t)row * D_ + qd);
  float4* po = (float4*)(out + (size_t)row * D_ + qd);
#pragma unroll
  for (int i = 0; i < 4; ++i) {
    float4 x = p0[i], y = p1[i];
    float4 r;
    r.x = x.x * w0 + y.x * w1; r.y = x.y * w0 + y.y * w1;
    r.z = x.z * w0 + y.z * w1; r.w = x.w * w0 + y.w * w1;
    po[i] = r;
  }
}

extern "C" void kernel_launch(void* const* d_in, const int* in_sizes, int n_in,
                              void* d_out, int out_size, void* d_ws, size_t ws_size,
                              hipStream_t stream) {
  const float* q_a = (const float*)d_in[0];
  const float* k_a = (const float*)d_in[1];
  const float* v_a = (const float*)d_in[2];
  const float* q_s = (const float*)d_in[3];
  const float* k_s = (const float*)d_in[4];
  const float* v_s = (const float*)d_in[5];
  const int*   mask = (const int*)d_in[6];
  float* out = (float*)d_out;
  (void)in_sizes; (void)n_in; (void)out_size; (void)ws_size;

  const int N = BH_ * S_ * D_;   // 4,194,304
  unsigned short* khat = (unsigned short*)d_ws;
  unsigned short* vt   = khat + N;
  int*  cnt  = (int*)(vt + N);           // 4 ints (16B-aligned pad)
  float* O1  = (float*)(cnt + 4);        // N floats (chunk-1 partial)
  float2* ml = (float2*)(O1 + N);        // NCH * BH_*S_ float2

  {
    dim3 g(S_ / 64, BH_);
    kvgather_kernel<<<g, 256, 0, stream>>>(k_a, k_s, v_a, v_s, mask, cnt, khat, vt);
  }
  {
    dim3 g(S_ / QBLK, BH_, NCH);
    attn_kernel<<<g, 256, 0, stream>>>(q_a, q_s, khat, vt, cnt, out, O1, ml);
  }
  combine_kernel<<<(BH_ * S_ * 4) / 256, 256, 0, stream>>>(O1, ml, out);
}

// Round 17
// 121.565 us; speedup vs baseline: 1.3099x; 1.0199x over previous
//
#include <hip/hip_runtime.h>
#include <hip/hip_bf16.h>

// (B,H,S,D) = (2,8,4096,64)
#define S_   4096
#define D_   64
#define BH_  16
#define QW   64        // q rows per wave (two 32-col MFMA blocks)
#define QBLK 256       // q rows per block (4 waves)
#define KVB  128       // keys per staged tile (two 64-key halves per barrier)
#define NCH  2         // kv chunks (grid z)

typedef __attribute__((ext_vector_type(8)))  short short8_t;   // 8 bf16 (MFMA A/B frag)
typedef __attribute__((ext_vector_type(16))) float f32x16;     // 32x32 MFMA C/D frag
#define QSCALE 0.18033688011112042f   /* (1/8)*log2(e): scores in log2 domain */

__device__ __forceinline__ unsigned short f2bf(float f) {
  unsigned u = __float_as_uint(f);
  u += 0x7fffu + ((u >> 16) & 1u);   // RTNE
  return (unsigned short)(u >> 16);
}

__device__ __forceinline__ void glds16(const unsigned short* g, unsigned short* l) {
  __builtin_amdgcn_global_load_lds(
      (const __attribute__((address_space(1))) unsigned int*)g,
      (__attribute__((address_space(3))) unsigned int*)l, 16, 0, 0);
}

// fused: per-batch mask scan (compact) + K/V gather + Q add/scale convert + V transpose.
// qhat[bh][r][d] bf16 (all rows), khat[bh][j][d] gathered, vt[bh][d][j] transposed.
__global__ void kvgather_kernel(const float* __restrict__ ka, const float* __restrict__ ks,
                                const float* __restrict__ va, const float* __restrict__ vs,
                                const float* __restrict__ qa, const float* __restrict__ qs,
                                const int* __restrict__ mask, int* __restrict__ cnt,
                                unsigned short* __restrict__ qhat,
                                unsigned short* __restrict__ khat,
                                unsigned short* __restrict__ vt) {
  __shared__ int ps[256];
  __shared__ int srcLds[64];
  __shared__ __align__(16) unsigned short t[D_][72];
  const int bh = blockIdx.y, b = bh >> 3;
  const int s0 = blockIdx.x * 64;
  const int tid = threadIdx.x;

  // ---- scan mask[b][*]: rank of each set bit; collect ranks in [s0, s0+64)
  const int* mb = mask + (size_t)b * S_;
  int m[16], c = 0;
  const int base = tid * 16;
#pragma unroll
  for (int i = 0; i < 16; ++i) { m[i] = mb[base + i]; c += (m[i] != 0); }
  ps[tid] = c;
  __syncthreads();
  for (int off = 1; off < 256; off <<= 1) {   // Hillis-Steele inclusive scan
    int add = (tid >= off) ? ps[tid - off] : 0;
    __syncthreads();
    ps[tid] += add;
    __syncthreads();
  }
  const int C = ps[255];
  int pos = ps[tid] - c;   // exclusive prefix
#pragma unroll
  for (int i = 0; i < 16; ++i) {
    if (m[i]) {
      int r = pos++;
      if (r >= s0 && r < s0 + 64) srcLds[r - s0] = base + i;
    }
  }
  if (tid == 0 && blockIdx.x == 0 && (bh & 7) == 0) cnt[b] = C;
  __syncthreads();

  const int row16 = tid >> 4;
  const int col4  = (tid & 15) * 4;
#pragma unroll
  for (int p = 0; p < 4; ++p) {
    int srow = p * 16 + row16;
    int j = s0 + srow;
    // ---- Q convert (ungathered, rows s0..s0+63 of this bh)
    {
      size_t qoff = ((size_t)bh * S_ + j) * D_ + col4;
      float4 xq = *(const float4*)(qa + qoff);
      float4 yq = *(const float4*)(qs + qoff);
      ushort4 rq;
      rq.x = f2bf((xq.x + yq.x) * QSCALE); rq.y = f2bf((xq.y + yq.y) * QSCALE);
      rq.z = f2bf((xq.z + yq.z) * QSCALE); rq.w = f2bf((xq.w + yq.w) * QSCALE);
      *(ushort4*)(qhat + qoff) = rq;
    }
    // ---- K/V gather + convert
    float4 xv = {0, 0, 0, 0}, yv = {0, 0, 0, 0};
    float4 xk = {0, 0, 0, 0}, yk = {0, 0, 0, 0};
    if (j < C) {
      int src = srcLds[srow];
      size_t off = ((size_t)bh * S_ + src) * D_ + col4;
      xv = *(const float4*)(va + off);
      yv = *(const float4*)(vs + off);
      xk = *(const float4*)(ka + off);
      yk = *(const float4*)(ks + off);
    }
    t[col4 + 0][srow] = f2bf(xv.x + yv.x);
    t[col4 + 1][srow] = f2bf(xv.y + yv.y);
    t[col4 + 2][srow] = f2bf(xv.z + yv.z);
    t[col4 + 3][srow] = f2bf(xv.w + yv.w);
    ushort4 rk;
    rk.x = f2bf(xk.x + yk.x); rk.y = f2bf(xk.y + yk.y);
    rk.z = f2bf(xk.z + yk.z); rk.w = f2bf(xk.w + yk.w);
    *(ushort4*)(khat + ((size_t)bh * S_ + j) * D_ + col4) = rk;
  }
  __syncthreads();
#pragma unroll
  for (int r = 0; r < 2; ++r) {
    int e = (r * 256 + tid) * 8;
    int d = e >> 6, sc = e & 63;
    short8_t v = *(const short8_t*)&t[d][sc];
    *(short8_t*)(vt + ((size_t)bh * D_ + d) * S_ + s0 + sc) = v;
  }
}

// Flash attention over compacted keys. Swapped-QK^T 32x32x16, two q-blocks/wave,
// 128-key tiles as two 64-key halves. R11-verified math; counted-vmcnt pipeline.
// Cross-lane exchange: __shfl_xor ONLY (inline permlane asm banned: R3/R5/R15 failures).
__global__ __launch_bounds__(256, 2) void attn_kernel(
    const unsigned short* __restrict__ Qb, const unsigned short* __restrict__ Kb,
    const unsigned short* __restrict__ Vt, const int* __restrict__ cnt,
    float* __restrict__ out, float* __restrict__ Opar, float2* __restrict__ Ml) {
  __shared__ __align__(16) unsigned short lK[2][KVB * 64];   // [key][d]
  __shared__ __align__(16) unsigned short lV[2][64 * KVB];   // [d][key]

  const int tid  = threadIdx.x;
  const int wave = tid >> 6;
  const int lane = tid & 63;
  const int l31  = lane & 31;
  const int h5   = lane >> 5;
  const int rsw  = l31 & 7;
  const int bh   = blockIdx.y;
  const int ch   = blockIdx.z;
  const int qrow0 = blockIdx.x * QBLK + wave * QW + l31;   // q-block 0; +32 for q-block 1
  const int b    = bh >> 3;
  const int C    = cnt[b];
  const int NTt  = (C + KVB - 1) / KVB;          // total 128-key tiles
  const int tpc  = (NTt + NCH - 1) / NCH;        // tiles per chunk
  const int ts   = ch * tpc;
  const int te   = (ts + tpc < NTt) ? (ts + tpc) : NTt;

  // Q fragments (B-operand): qf[qb][t4] = Q[qrow0 + 32*qb][t4*16 + h5*8 .. +7]
  short8_t qf[2][4];
#pragma unroll
  for (int qb = 0; qb < 2; ++qb) {
    const unsigned short* qp = Qb + ((size_t)bh * S_ + qrow0 + 32 * qb) * D_ + h5 * 8;
#pragma unroll
    for (int t4 = 0; t4 < 4; ++t4) qf[qb][t4] = *(const short8_t*)(qp + t4 * 16);
  }

  const unsigned short* gk0 = Kb + (size_t)bh * S_ * D_;
  const unsigned short* gv0 = Vt + (size_t)bh * D_ * S_;

  // staging geometry (1024 16B-chunks per tile per tensor; 4 per thread):
  // K [128 key rows][8 groups]: row=c>>3, src group = (c&7)^(row&7)   [m173 pattern]
  // V [64 d rows][16 groups]:   row=c>>4, src group = (g&8)|((g&7)^(row&7))
  int srcK[4], srcV[4], ldsB[4];
#pragma unroll
  for (int r2 = 0; r2 < 4; ++r2) {
    int c = r2 * 256 + tid;
    int rowK = c >> 3, gK = (c & 7) ^ (rowK & 7);
    srcK[r2] = rowK * 64 + gK * 8;
    int rowV = c >> 4, gg = c & 15;
    int swg = (gg & 8) | ((gg & 7) ^ (rowV & 7));
    srcV[r2] = rowV * S_ + swg * 8;
    ldsB[r2] = r2 * 2048 + wave * 512;   // wave-uniform base (elems); HW adds lane*16B
  }

  f32x16 acc0[2], acc1[2];
  float mrow[2], lrow[2];
#pragma unroll
  for (int qb = 0; qb < 2; ++qb) {
    acc0[qb] = (f32x16)(0.0f); acc1[qb] = (f32x16)(0.0f);
    mrow[qb] = -1e30f; lrow[qb] = 0.0f;
  }

  if (ts < te) {
    // prologue: issue tile-ts loads into buf0 (8 per wave); no drain here
#pragma unroll
    for (int r2 = 0; r2 < 4; ++r2) {
      glds16(gk0 + (size_t)ts * KVB * D_ + srcK[r2], &lK[0][ldsB[r2]]);
      glds16(gv0 + ts * KVB + srcV[r2], &lV[0][ldsB[r2]]);
    }

    for (int t = ts; t < te; ++t) {
      const int cur = (t - ts) & 1;
      if (t + 1 < te) {
        // issue next-tile loads (8) THEN wait for the previous 8 only (counted vmcnt)
#pragma unroll
        for (int r2 = 0; r2 < 4; ++r2) {
          glds16(gk0 + (size_t)(t + 1) * KVB * D_ + srcK[r2], &lK[cur ^ 1][ldsB[r2]]);
          glds16(gv0 + (t + 1) * KVB + srcV[r2], &lV[cur ^ 1][ldsB[r2]]);
        }
        asm volatile("s_waitcnt vmcnt(8)" ::: "memory");
      } else {
        asm volatile("s_waitcnt vmcnt(0)" ::: "memory");
      }
      __builtin_amdgcn_s_barrier();          // tile t visible to all waves (no drain)
      __builtin_amdgcn_sched_barrier(0);     // pin ds_reads below the barrier

#pragma unroll
      for (int h = 0; h < 2; ++h) {   // two 64-key halves of the staged tile
        // ---- S^T = K Q^T : K-frags shared across both q-blocks
        f32x16 sv0[2], sv1[2];
#pragma unroll
        for (int qb = 0; qb < 2; ++qb) { sv0[qb] = (f32x16)(0.0f); sv1[qb] = (f32x16)(0.0f); }
        __builtin_amdgcn_s_setprio(1);
#pragma unroll
        for (int t4 = 0; t4 < 4; ++t4) {
          int g = ((2 * t4 + h5) ^ rsw) * 8;
          short8_t kf0 = *(const short8_t*)&lK[cur][(h * 64 + l31) * 64 + g];
          short8_t kf1 = *(const short8_t*)&lK[cur][(h * 64 + 32 + l31) * 64 + g];
          sv0[0] = __builtin_amdgcn_mfma_f32_32x32x16_bf16(kf0, qf[0][t4], sv0[0], 0, 0, 0);
          sv0[1] = __builtin_amdgcn_mfma_f32_32x32x16_bf16(kf0, qf[1][t4], sv0[1], 0, 0, 0);
          sv1[0] = __builtin_amdgcn_mfma_f32_32x32x16_bf16(kf1, qf[0][t4], sv1[0], 0, 0, 0);
          sv1[1] = __builtin_amdgcn_mfma_f32_32x32x16_bf16(kf1, qf[1][t4], sv1[1], 0, 0, 0);
        }
        __builtin_amdgcn_s_setprio(0);

        // ---- tail: pad keys (key >= C) -> -1e9 (reg->key mapping, no memory)
        if (t == NTt - 1) {
          int kvb = t * KVB + h * 64;
#pragma unroll
          for (int i = 0; i < 16; ++i) {
            int key = kvb + (i & 3) + 8 * (i >> 2) + 4 * h5;
#pragma unroll
            for (int qb = 0; qb < 2; ++qb) {
              if (key >= C) sv0[qb][i] = -1e9f;
              if (key + 32 >= C) sv1[qb][i] = -1e9f;
            }
          }
        }

        // ---- online softmax per q-block (in-register, log2 domain)
        unsigned int pkw[2][16];
#pragma unroll
        for (int qb = 0; qb < 2; ++qb) {
          float tmx[8];
#pragma unroll
          for (int i = 0; i < 8; ++i)
            tmx[i] = fmaxf(fmaxf(sv0[qb][i], sv0[qb][i + 8]),
                           fmaxf(sv1[qb][i], sv1[qb][i + 8]));
#pragma unroll
          for (int i = 0; i < 4; ++i) tmx[i] = fmaxf(tmx[i], tmx[i + 4]);
          float tm = fmaxf(fmaxf(tmx[0], tmx[1]), fmaxf(tmx[2], tmx[3]));
          tm = fmaxf(tm, __shfl_xor(tm, 32));

          if (__any(tm > mrow[qb] + 8.0f)) {   // defer-max (T13)
            float mnew = fmaxf(mrow[qb], tm);
            float sc = __builtin_amdgcn_exp2f(mrow[qb] - mnew);
            mrow[qb] = mnew;
            lrow[qb] *= sc;
#pragma unroll
            for (int i = 0; i < 16; ++i) { acc0[qb][i] *= sc; acc1[qb][i] *= sc; }
          }

          float m = mrow[qb];
          float t0 = 0.f, t1 = 0.f, t2 = 0.f, t3 = 0.f;
#pragma unroll
          for (int i = 0; i < 16; i += 4) {
            sv0[qb][i + 0] = __builtin_amdgcn_exp2f(sv0[qb][i + 0] - m); t0 += sv0[qb][i + 0];
            sv0[qb][i + 1] = __builtin_amdgcn_exp2f(sv0[qb][i + 1] - m); t1 += sv0[qb][i + 1];
            sv0[qb][i + 2] = __builtin_amdgcn_exp2f(sv0[qb][i + 2] - m); t2 += sv0[qb][i + 2];
            sv0[qb][i + 3] = __builtin_amdgcn_exp2f(sv0[qb][i + 3] - m); t3 += sv0[qb][i + 3];
            sv1[qb][i + 0] = __builtin_amdgcn_exp2f(sv1[qb][i + 0] - m); t0 += sv1[qb][i + 0];
            sv1[qb][i + 1] = __builtin_amdgcn_exp2f(sv1[qb][i + 1] - m); t1 += sv1[qb][i + 1];
            sv1[qb][i + 2] = __builtin_amdgcn_exp2f(sv1[qb][i + 2] - m); t2 += sv1[qb][i + 2];
            sv1[qb][i + 3] = __builtin_amdgcn_exp2f(sv1[qb][i + 3] - m); t3 += sv1[qb][i + 3];
          }
          float tsum = (t0 + t1) + (t2 + t3);
          tsum += __shfl_xor(tsum, 32);
          lrow[qb] += tsum;

          // pack: pkw[qb][n*8+rg*2+c] = keys n*32 + rg*8 + 4*h5 + 2c, +1
#pragma unroll
          for (int rg = 0; rg < 4; ++rg) {
            __hip_bfloat162 a0 = __float22bfloat162_rn({sv0[qb][rg * 4 + 0], sv0[qb][rg * 4 + 1]});
            __hip_bfloat162 a1 = __float22bfloat162_rn({sv0[qb][rg * 4 + 2], sv0[qb][rg * 4 + 3]});
            __hip_bfloat162 b0 = __float22bfloat162_rn({sv1[qb][rg * 4 + 0], sv1[qb][rg * 4 + 1]});
            __hip_bfloat162 b1 = __float22bfloat162_rn({sv1[qb][rg * 4 + 2], sv1[qb][rg * 4 + 3]});
            pkw[qb][rg * 2 + 0] = *(unsigned int*)&a0;
            pkw[qb][rg * 2 + 1] = *(unsigned int*)&a1;
            pkw[qb][8 + rg * 2 + 0] = *(unsigned int*)&b0;
            pkw[qb][8 + rg * 2 + 1] = *(unsigned int*)&b1;
          }
        }

        // ---- O^T += V^T P : half-swap redistribution via shfl (R4-verified mapping)
        __builtin_amdgcn_s_setprio(1);
#pragma unroll
        for (int kt = 0; kt < 4; ++kt) {
          const int n = kt >> 1, k1 = kt & 1;
          int gcol = ((h * 8) | ((2 * kt + h5) ^ rsw)) * 8;
          short8_t vf0 = *(const short8_t*)&lV[cur][l31 * KVB + gcol];
          short8_t vf1 = *(const short8_t*)&lV[cur][(32 + l31) * KVB + gcol];
#pragma unroll
          for (int qb = 0; qb < 2; ++qb) {
            unsigned int sA = pkw[qb][n * 8 + (2 * k1 + h5) * 2 + 0];
            unsigned int sB = pkw[qb][n * 8 + (2 * k1 + h5) * 2 + 1];
            unsigned int xA = pkw[qb][n * 8 + (2 * k1 + (h5 ^ 1)) * 2 + 0];
            unsigned int xB = pkw[qb][n * 8 + (2 * k1 + (h5 ^ 1)) * 2 + 1];
            unsigned int pA = (unsigned int)__shfl_xor((int)xA, 32);
            unsigned int pB = (unsigned int)__shfl_xor((int)xB, 32);
            union { unsigned int u[4]; short8_t v; } bb;
            bb.u[0] = h5 ? pA : sA;
            bb.u[1] = h5 ? pB : sB;
            bb.u[2] = h5 ? sA : pA;
            bb.u[3] = h5 ? sB : pB;
            acc0[qb] = __builtin_amdgcn_mfma_f32_32x32x16_bf16(vf0, bb.v, acc0[qb], 0, 0, 0);
            acc1[qb] = __builtin_amdgcn_mfma_f32_32x32x16_bf16(vf1, bb.v, acc1[qb], 0, 0, 0);
          }
        }
        __builtin_amdgcn_s_setprio(0);
      }

      __builtin_amdgcn_sched_barrier(0);
      __builtin_amdgcn_s_barrier();   // all waves done reading buf[cur] before next glds
    }
  }

  // ---- epilogue: unnormalized partial O + (m,l) stats, per q-block
  float* Op = (ch == 0) ? out : Opar;
#pragma unroll
  for (int qb = 0; qb < 2; ++qb) {
    float* op = Op + ((size_t)bh * S_ + qrow0 + 32 * qb) * D_;
#pragma unroll
    for (int rg = 0; rg < 4; ++rg) {
      float4 o0, o1;
      o0.x = acc0[qb][rg * 4 + 0]; o0.y = acc0[qb][rg * 4 + 1];
      o0.z = acc0[qb][rg * 4 + 2]; o0.w = acc0[qb][rg * 4 + 3];
      o1.x = acc1[qb][rg * 4 + 0]; o1.y = acc1[qb][rg * 4 + 1];
      o1.z = acc1[qb][rg * 4 + 2]; o1.w = acc1[qb][rg * 4 + 3];
      *(float4*)(op + rg * 8 + h5 * 4) = o0;
      *(float4*)(op + 32 + rg * 8 + h5 * 4) = o1;
    }
    if (h5 == 0) {
      float2 st; st.x = mrow[qb]; st.y = lrow[qb];
      Ml[(size_t)ch * (BH_ * S_) + (size_t)bh * S_ + qrow0 + 32 * qb] = st;
    }
  }
}

// merge 2 KV-chunk partials: out = (O0*w0 + O1*w1) / (l0*w0 + l1*w1), wi = 2^(mi - M)
__global__ void combine_kernel(const float* __restrict__ O1, const float2* __restrict__ Ml,
                               float* __restrict__ out) {
  int gid = blockIdx.x * 256 + threadIdx.x;   // (row, 16-d quarter)
  int row = gid >> 2, qd = (gid & 3) * 16;
  float2 a = Ml[row];                    // chunk 0
  float2 b = Ml[BH_ * S_ + row];         // chunk 1
  float M = fmaxf(a.x, b.x);
  float w0 = exp2f(a.x - M), w1 = exp2f(b.x - M);
  float inv = 1.0f / (a.y * w0 + b.y * w1);
  w0 *= inv; w1 *= inv;
  const float4* p0 = (const float4*)(out + (size_t)row * D_ + qd);  // chunk0 partial in out
  const float4* p1 = (const float4*)(O1 + (size_t)row * D_ + qd);
  float4* po = (float4*)(out + (size_t)row * D_ + qd);
#pragma unroll
  for (int i = 0; i < 4; ++i) {
    float4 x = p0[i], y = p1[i];
    float4 r;
    r.x = x.x * w0 + y.x * w1; r.y = x.y * w0 + y.y * w1;
    r.z = x.z * w0 + y.z * w1; r.w = x.w * w0 + y.w * w1;
    po[i] = r;
  }
}

extern "C" void kernel_launch(void* const* d_in, const int* in_sizes, int n_in,
                              void* d_out, int out_size, void* d_ws, size_t ws_size,
                              hipStream_t stream) {
  const float* q_a = (const float*)d_in[0];
  const float* k_a = (const float*)d_in[1];
  const float* v_a = (const float*)d_in[2];
  const float* q_s = (const float*)d_in[3];
  const float* k_s = (const float*)d_in[4];
  const float* v_s = (const float*)d_in[5];
  const int*   mask = (const int*)d_in[6];
  float* out = (float*)d_out;
  (void)in_sizes; (void)n_in; (void)out_size; (void)ws_size;

  const int N = BH_ * S_ * D_;   // 4,194,304
  unsigned short* qhat = (unsigned short*)d_ws;
  unsigned short* khat = qhat + N;
  unsigned short* vt   = khat + N;
  int*  cnt  = (int*)(vt + N);           // 4 ints (16B-aligned pad)
  float* O1  = (float*)(cnt + 4);        // N floats (chunk-1 partial)
  float2* ml = (float2*)(O1 + N);        // NCH * BH_*S_ float2

  {
    dim3 g(S_ / 64, BH_);
    kvgather_kernel<<<g, 256, 0, stream>>>(k_a, k_s, v_a, v_s, q_a, q_s, mask, cnt,
                                           qhat, khat, vt);
  }
  {
    dim3 g(S_ / QBLK, BH_, NCH);
    attn_kernel<<<g, 256, 0, stream>>>(qhat, khat, vt, cnt, out, O1, ml);
  }
  combine_kernel<<<(BH_ * S_ * 4) / 256, 256, 0, stream>>>(O1, ml, out);
}

// Round 18
// 119.238 us; speedup vs baseline: 1.3354x; 1.0195x over previous
//
#include <hip/hip_runtime.h>
#include <hip/hip_bf16.h>

// (B,H,S,D) = (2,8,4096,64)
#define S_   4096
#define D_   64
#define BH_  16
#define QW   64        // q rows per wave (two 32-col MFMA blocks)
#define QBLK 256       // q rows per block (4 waves)
#define KVB  128       // keys per staged tile (two 64-key halves per barrier)
#define NCH  2         // kv chunks (grid z)

typedef __attribute__((ext_vector_type(8)))  short short8_t;   // 8 bf16 (MFMA A/B frag)
typedef __attribute__((ext_vector_type(16))) float f32x16;     // 32x32 MFMA C/D frag
#define QSCALE 0.18033688011112042f   /* (1/8)*log2(e): scores in log2 domain */

__device__ __forceinline__ unsigned short f2bf(float f) {
  unsigned u = __float_as_uint(f);
  u += 0x7fffu + ((u >> 16) & 1u);   // RTNE
  return (unsigned short)(u >> 16);
}

__device__ __forceinline__ void glds16(const unsigned short* g, unsigned short* l) {
  __builtin_amdgcn_global_load_lds(
      (const __attribute__((address_space(1))) unsigned int*)g,
      (__attribute__((address_space(3))) unsigned int*)l, 16, 0, 0);
}

// fused: per-batch mask scan (compact) + K/V gather + Q add/scale convert + V transpose.
// qhat[bh][r][d] bf16 (all rows), khat[bh][j][d] gathered, vt[bh][d][j] transposed.
__global__ void kvgather_kernel(const float* __restrict__ ka, const float* __restrict__ ks,
                                const float* __restrict__ va, const float* __restrict__ vs,
                                const float* __restrict__ qa, const float* __restrict__ qs,
                                const int* __restrict__ mask, int* __restrict__ cnt,
                                unsigned short* __restrict__ qhat,
                                unsigned short* __restrict__ khat,
                                unsigned short* __restrict__ vt) {
  __shared__ int ps[256];
  __shared__ int srcLds[64];
  __shared__ __align__(16) unsigned short t[D_][72];
  const int bh = blockIdx.y, b = bh >> 3;
  const int s0 = blockIdx.x * 64;
  const int tid = threadIdx.x;

  // ---- scan mask[b][*]: rank of each set bit; collect ranks in [s0, s0+64)
  const int* mb = mask + (size_t)b * S_;
  int m[16], c = 0;
  const int base = tid * 16;
#pragma unroll
  for (int i = 0; i < 16; ++i) { m[i] = mb[base + i]; c += (m[i] != 0); }
  ps[tid] = c;
  __syncthreads();
  for (int off = 1; off < 256; off <<= 1) {   // Hillis-Steele inclusive scan
    int add = (tid >= off) ? ps[tid - off] : 0;
    __syncthreads();
    ps[tid] += add;
    __syncthreads();
  }
  const int C = ps[255];
  int pos = ps[tid] - c;   // exclusive prefix
#pragma unroll
  for (int i = 0; i < 16; ++i) {
    if (m[i]) {
      int r = pos++;
      if (r >= s0 && r < s0 + 64) srcLds[r - s0] = base + i;
    }
  }
  if (tid == 0 && blockIdx.x == 0 && (bh & 7) == 0) cnt[b] = C;
  __syncthreads();

  const int row16 = tid >> 4;
  const int col4  = (tid & 15) * 4;
#pragma unroll
  for (int p = 0; p < 4; ++p) {
    int srow = p * 16 + row16;
    int j = s0 + srow;
    // ---- Q convert (ungathered, rows s0..s0+63 of this bh)
    {
      size_t qoff = ((size_t)bh * S_ + j) * D_ + col4;
      float4 xq = *(const float4*)(qa + qoff);
      float4 yq = *(const float4*)(qs + qoff);
      ushort4 rq;
      rq.x = f2bf((xq.x + yq.x) * QSCALE); rq.y = f2bf((xq.y + yq.y) * QSCALE);
      rq.z = f2bf((xq.z + yq.z) * QSCALE); rq.w = f2bf((xq.w + yq.w) * QSCALE);
      *(ushort4*)(qhat + qoff) = rq;
    }
    // ---- K/V gather + convert
    float4 xv = {0, 0, 0, 0}, yv = {0, 0, 0, 0};
    float4 xk = {0, 0, 0, 0}, yk = {0, 0, 0, 0};
    if (j < C) {
      int src = srcLds[srow];
      size_t off = ((size_t)bh * S_ + src) * D_ + col4;
      xv = *(const float4*)(va + off);
      yv = *(const float4*)(vs + off);
      xk = *(const float4*)(ka + off);
      yk = *(const float4*)(ks + off);
    }
    t[col4 + 0][srow] = f2bf(xv.x + yv.x);
    t[col4 + 1][srow] = f2bf(xv.y + yv.y);
    t[col4 + 2][srow] = f2bf(xv.z + yv.z);
    t[col4 + 3][srow] = f2bf(xv.w + yv.w);
    ushort4 rk;
    rk.x = f2bf(xk.x + yk.x); rk.y = f2bf(xk.y + yk.y);
    rk.z = f2bf(xk.z + yk.z); rk.w = f2bf(xk.w + yk.w);
    *(ushort4*)(khat + ((size_t)bh * S_ + j) * D_ + col4) = rk;
  }
  __syncthreads();
#pragma unroll
  for (int r = 0; r < 2; ++r) {
    int e = (r * 256 + tid) * 8;
    int d = e >> 6, sc = e & 63;
    short8_t v = *(const short8_t*)&t[d][sc];
    *(short8_t*)(vt + ((size_t)bh * D_ + d) * S_ + s0 + sc) = v;
  }
}

// Flash attention over compacted keys. Swapped-QK^T 32x32x16, two q-blocks/wave,
// 128-key tiles as two 64-key halves. R11-verified math; counted-vmcnt pipeline.
// Row-sum computed on the MATRIX pipe via constant all-ones A-fragment MFMA
// (every output reg = colsum of P; reg0 tracked as lrow; rescale touches reg0 only).
// Cross-lane exchange: __shfl_xor ONLY (inline permlane asm banned: R3/R5/R15 failures).
__global__ __launch_bounds__(256, 2) void attn_kernel(
    const unsigned short* __restrict__ Qb, const unsigned short* __restrict__ Kb,
    const unsigned short* __restrict__ Vt, const int* __restrict__ cnt,
    float* __restrict__ out, float* __restrict__ Opar, float2* __restrict__ Ml) {
  __shared__ __align__(16) unsigned short lK[2][KVB * 64];   // [key][d]
  __shared__ __align__(16) unsigned short lV[2][64 * KVB];   // [d][key]

  const int tid  = threadIdx.x;
  const int wave = tid >> 6;
  const int lane = tid & 63;
  const int l31  = lane & 31;
  const int h5   = lane >> 5;
  const int rsw  = l31 & 7;
  const int bh   = blockIdx.y;
  const int ch   = blockIdx.z;
  const int qrow0 = blockIdx.x * QBLK + wave * QW + l31;   // q-block 0; +32 for q-block 1
  const int b    = bh >> 3;
  const int C    = cnt[b];
  const int NTt  = (C + KVB - 1) / KVB;          // total 128-key tiles
  const int tpc  = (NTt + NCH - 1) / NCH;        // tiles per chunk
  const int ts   = ch * tpc;
  const int te   = (ts + tpc < NTt) ? (ts + tpc) : NTt;

  // Q fragments (B-operand): qf[qb][t4] = Q[qrow0 + 32*qb][t4*16 + h5*8 .. +7]
  short8_t qf[2][4];
#pragma unroll
  for (int qb = 0; qb < 2; ++qb) {
    const unsigned short* qp = Qb + ((size_t)bh * S_ + qrow0 + 32 * qb) * D_ + h5 * 8;
#pragma unroll
    for (int t4 = 0; t4 < 4; ++t4) qf[qb][t4] = *(const short8_t*)(qp + t4 * 16);
  }

  // constant all-ones bf16 A-fragment for the sum MFMA
  short8_t ones8;
#pragma unroll
  for (int i = 0; i < 8; ++i) ones8[i] = (short)0x3F80;

  const unsigned short* gk0 = Kb + (size_t)bh * S_ * D_;
  const unsigned short* gv0 = Vt + (size_t)bh * D_ * S_;

  // staging geometry (1024 16B-chunks per tile per tensor; 4 per thread):
  // K [128 key rows][8 groups]: row=c>>3, src group = (c&7)^(row&7)   [m173 pattern]
  // V [64 d rows][16 groups]:   row=c>>4, src group = (g&8)|((g&7)^(row&7))
  int srcK[4], srcV[4], ldsB[4];
#pragma unroll
  for (int r2 = 0; r2 < 4; ++r2) {
    int c = r2 * 256 + tid;
    int rowK = c >> 3, gK = (c & 7) ^ (rowK & 7);
    srcK[r2] = rowK * 64 + gK * 8;
    int rowV = c >> 4, gg = c & 15;
    int swg = (gg & 8) | ((gg & 7) ^ (rowV & 7));
    srcV[r2] = rowV * S_ + swg * 8;
    ldsB[r2] = r2 * 2048 + wave * 512;   // wave-uniform base (elems); HW adds lane*16B
  }

  f32x16 acc0[2], acc1[2], accS[2];
  float mrow[2];
#pragma unroll
  for (int qb = 0; qb < 2; ++qb) {
    acc0[qb] = (f32x16)(0.0f); acc1[qb] = (f32x16)(0.0f); accS[qb] = (f32x16)(0.0f);
    mrow[qb] = -1e30f;
  }

  if (ts < te) {
    // prologue: issue tile-ts loads into buf0 (8 per wave); no drain here
#pragma unroll
    for (int r2 = 0; r2 < 4; ++r2) {
      glds16(gk0 + (size_t)ts * KVB * D_ + srcK[r2], &lK[0][ldsB[r2]]);
      glds16(gv0 + ts * KVB + srcV[r2], &lV[0][ldsB[r2]]);
    }

    for (int t = ts; t < te; ++t) {
      const int cur = (t - ts) & 1;
      if (t + 1 < te) {
        // issue next-tile loads (8) THEN wait for the previous 8 only (counted vmcnt)
#pragma unroll
        for (int r2 = 0; r2 < 4; ++r2) {
          glds16(gk0 + (size_t)(t + 1) * KVB * D_ + srcK[r2], &lK[cur ^ 1][ldsB[r2]]);
          glds16(gv0 + (t + 1) * KVB + srcV[r2], &lV[cur ^ 1][ldsB[r2]]);
        }
        asm volatile("s_waitcnt vmcnt(8)" ::: "memory");
      } else {
        asm volatile("s_waitcnt vmcnt(0)" ::: "memory");
      }
      __builtin_amdgcn_s_barrier();          // tile t visible to all waves (no drain)
      __builtin_amdgcn_sched_barrier(0);     // pin ds_reads below the barrier

#pragma unroll
      for (int h = 0; h < 2; ++h) {   // two 64-key halves of the staged tile
        // ---- S^T = K Q^T : K-frags shared across both q-blocks
        f32x16 sv0[2], sv1[2];
#pragma unroll
        for (int qb = 0; qb < 2; ++qb) { sv0[qb] = (f32x16)(0.0f); sv1[qb] = (f32x16)(0.0f); }
        __builtin_amdgcn_s_setprio(1);
#pragma unroll
        for (int t4 = 0; t4 < 4; ++t4) {
          int g = ((2 * t4 + h5) ^ rsw) * 8;
          short8_t kf0 = *(const short8_t*)&lK[cur][(h * 64 + l31) * 64 + g];
          short8_t kf1 = *(const short8_t*)&lK[cur][(h * 64 + 32 + l31) * 64 + g];
          sv0[0] = __builtin_amdgcn_mfma_f32_32x32x16_bf16(kf0, qf[0][t4], sv0[0], 0, 0, 0);
          sv0[1] = __builtin_amdgcn_mfma_f32_32x32x16_bf16(kf0, qf[1][t4], sv0[1], 0, 0, 0);
          sv1[0] = __builtin_amdgcn_mfma_f32_32x32x16_bf16(kf1, qf[0][t4], sv1[0], 0, 0, 0);
          sv1[1] = __builtin_amdgcn_mfma_f32_32x32x16_bf16(kf1, qf[1][t4], sv1[1], 0, 0, 0);
        }
        __builtin_amdgcn_s_setprio(0);

        // ---- tail: pad keys (key >= C) -> -1e9 (reg->key mapping, no memory)
        if (t == NTt - 1) {
          int kvb = t * KVB + h * 64;
#pragma unroll
          for (int i = 0; i < 16; ++i) {
            int key = kvb + (i & 3) + 8 * (i >> 2) + 4 * h5;
#pragma unroll
            for (int qb = 0; qb < 2; ++qb) {
              if (key >= C) sv0[qb][i] = -1e9f;
              if (key + 32 >= C) sv1[qb][i] = -1e9f;
            }
          }
        }

        // ---- online softmax per q-block (in-register, log2 domain)
        unsigned int pkw[2][16];
#pragma unroll
        for (int qb = 0; qb < 2; ++qb) {
          float tmx[8];
#pragma unroll
          for (int i = 0; i < 8; ++i)
            tmx[i] = fmaxf(fmaxf(sv0[qb][i], sv0[qb][i + 8]),
                           fmaxf(sv1[qb][i], sv1[qb][i + 8]));
#pragma unroll
          for (int i = 0; i < 4; ++i) tmx[i] = fmaxf(tmx[i], tmx[i + 4]);
          float tm = fmaxf(fmaxf(tmx[0], tmx[1]), fmaxf(tmx[2], tmx[3]));
          tm = fmaxf(tm, __shfl_xor(tm, 32));

          if (__any(tm > mrow[qb] + 8.0f)) {   // defer-max (T13)
            float mnew = fmaxf(mrow[qb], tm);
            float sc = __builtin_amdgcn_exp2f(mrow[qb] - mnew);
            mrow[qb] = mnew;
            accS[qb][0] *= sc;                 // only reg0 of the sum acc is tracked
#pragma unroll
            for (int i = 0; i < 16; ++i) { acc0[qb][i] *= sc; acc1[qb][i] *= sc; }
          }

          float m = mrow[qb];
#pragma unroll
          for (int i = 0; i < 16; i += 4) {
            sv0[qb][i + 0] = __builtin_amdgcn_exp2f(sv0[qb][i + 0] - m);
            sv0[qb][i + 1] = __builtin_amdgcn_exp2f(sv0[qb][i + 1] - m);
            sv0[qb][i + 2] = __builtin_amdgcn_exp2f(sv0[qb][i + 2] - m);
            sv0[qb][i + 3] = __builtin_amdgcn_exp2f(sv0[qb][i + 3] - m);
            sv1[qb][i + 0] = __builtin_amdgcn_exp2f(sv1[qb][i + 0] - m);
            sv1[qb][i + 1] = __builtin_amdgcn_exp2f(sv1[qb][i + 1] - m);
            sv1[qb][i + 2] = __builtin_amdgcn_exp2f(sv1[qb][i + 2] - m);
            sv1[qb][i + 3] = __builtin_amdgcn_exp2f(sv1[qb][i + 3] - m);
          }

          // pack: pkw[qb][n*8+rg*2+c] = keys n*32 + rg*8 + 4*h5 + 2c, +1
#pragma unroll
          for (int rg = 0; rg < 4; ++rg) {
            __hip_bfloat162 a0 = __float22bfloat162_rn({sv0[qb][rg * 4 + 0], sv0[qb][rg * 4 + 1]});
            __hip_bfloat162 a1 = __float22bfloat162_rn({sv0[qb][rg * 4 + 2], sv0[qb][rg * 4 + 3]});
            __hip_bfloat162 b0 = __float22bfloat162_rn({sv1[qb][rg * 4 + 0], sv1[qb][rg * 4 + 1]});
            __hip_bfloat162 b1 = __float22bfloat162_rn({sv1[qb][rg * 4 + 2], sv1[qb][rg * 4 + 3]});
            pkw[qb][rg * 2 + 0] = *(unsigned int*)&a0;
            pkw[qb][rg * 2 + 1] = *(unsigned int*)&a1;
            pkw[qb][8 + rg * 2 + 0] = *(unsigned int*)&b0;
            pkw[qb][8 + rg * 2 + 1] = *(unsigned int*)&b1;
          }
        }

        // ---- O^T += V^T P (+ row-sum via ones-MFMA): shfl redistribution (R4-verified)
        __builtin_amdgcn_s_setprio(1);
#pragma unroll
        for (int kt = 0; kt < 4; ++kt) {
          const int n = kt >> 1, k1 = kt & 1;
          int gcol = ((h * 8) | ((2 * kt + h5) ^ rsw)) * 8;
          short8_t vf0 = *(const short8_t*)&lV[cur][l31 * KVB + gcol];
          short8_t vf1 = *(const short8_t*)&lV[cur][(32 + l31) * KVB + gcol];
#pragma unroll
          for (int qb = 0; qb < 2; ++qb) {
            unsigned int sA = pkw[qb][n * 8 + (2 * k1 + h5) * 2 + 0];
            unsigned int sB = pkw[qb][n * 8 + (2 * k1 + h5) * 2 + 1];
            unsigned int xA = pkw[qb][n * 8 + (2 * k1 + (h5 ^ 1)) * 2 + 0];
            unsigned int xB = pkw[qb][n * 8 + (2 * k1 + (h5 ^ 1)) * 2 + 1];
            unsigned int pA = (unsigned int)__shfl_xor((int)xA, 32);
            unsigned int pB = (unsigned int)__shfl_xor((int)xB, 32);
            union { unsigned int u[4]; short8_t v; } bb;
            bb.u[0] = h5 ? pA : sA;
            bb.u[1] = h5 ? pB : sB;
            bb.u[2] = h5 ? sA : pA;
            bb.u[3] = h5 ? sB : pB;
            acc0[qb] = __builtin_amdgcn_mfma_f32_32x32x16_bf16(vf0, bb.v, acc0[qb], 0, 0, 0);
            acc1[qb] = __builtin_amdgcn_mfma_f32_32x32x16_bf16(vf1, bb.v, acc1[qb], 0, 0, 0);
            accS[qb] = __builtin_amdgcn_mfma_f32_32x32x16_bf16(ones8, bb.v, accS[qb], 0, 0, 0);
          }
        }
        __builtin_amdgcn_s_setprio(0);
      }

      __builtin_amdgcn_sched_barrier(0);
      __builtin_amdgcn_s_barrier();   // all waves done reading buf[cur] before next glds
    }
  }

  // ---- epilogue: unnormalized partial O + (m,l) stats, per q-block
  float* Op = (ch == 0) ? out : Opar;
#pragma unroll
  for (int qb = 0; qb < 2; ++qb) {
    float* op = Op + ((size_t)bh * S_ + qrow0 + 32 * qb) * D_;
#pragma unroll
    for (int rg = 0; rg < 4; ++rg) {
      float4 o0, o1;
      o0.x = acc0[qb][rg * 4 + 0]; o0.y = acc0[qb][rg * 4 + 1];
      o0.z = acc0[qb][rg * 4 + 2]; o0.w = acc0[qb][rg * 4 + 3];
      o1.x = acc1[qb][rg * 4 + 0]; o1.y = acc1[qb][rg * 4 + 1];
      o1.z = acc1[qb][rg * 4 + 2]; o1.w = acc1[qb][rg * 4 + 3];
      *(float4*)(op + rg * 8 + h5 * 4) = o0;
      *(float4*)(op + 32 + rg * 8 + h5 * 4) = o1;
    }
    if (h5 == 0) {
      float2 st; st.x = mrow[qb]; st.y = accS[qb][0];   // lrow from ones-MFMA
      Ml[(size_t)ch * (BH_ * S_) + (size_t)bh * S_ + qrow0 + 32 * qb] = st;
    }
  }
}

// merge 2 KV-chunk partials: out = (O0*w0 + O1*w1) / (l0*w0 + l1*w1), wi = 2^(mi - M)
__global__ void combine_kernel(const float* __restrict__ O1, const float2* __restrict__ Ml,
                               float* __restrict__ out) {
  int gid = blockIdx.x * 256 + threadIdx.x;   // (row, 16-d quarter)
  int row = gid >> 2, qd = (gid & 3) * 16;
  float2 a = Ml[row];                    // chunk 0
  float2 b = Ml[BH_ * S_ + row];         // chunk 1
  float M = fmaxf(a.x, b.x);
  float w0 = exp2f(a.x - M), w1 = exp2f(b.x - M);
  float inv = 1.0f / (a.y * w0 + b.y * w1);
  w0 *= inv; w1 *= inv;
  const float4* p0 = (const float4*)(out + (size_t)row * D_ + qd);  // chunk0 partial in out
  const float4* p1 = (const float4*)(O1 + (size_t)row * D_ + qd);
  float4* po = (float4*)(out + (size_t)row * D_ + qd);
#pragma unroll
  for (int i = 0; i < 4; ++i) {
    float4 x = p0[i], y = p1[i];
    float4 r;
    r.x = x.x * w0 + y.x * w1; r.y = x.y * w0 + y.y * w1;
    r.z = x.z * w0 + y.z * w1; r.w = x.w * w0 + y.w * w1;
    po[i] = r;
  }
}

extern "C" void kernel_launch(void* const* d_in, const int* in_sizes, int n_in,
                              void* d_out, int out_size, void* d_ws, size_t ws_size,
                              hipStream_t stream) {
  const float* q_a = (const float*)d_in[0];
  const float* k_a = (const float*)d_in[1];
  const float* v_a = (const float*)d_in[2];
  const float* q_s = (const float*)d_in[3];
  const float* k_s = (const float*)d_in[4];
  const float* v_s = (const float*)d_in[5];
  const int*   mask = (const int*)d_in[6];
  float* out = (float*)d_out;
  (void)in_sizes; (void)n_in; (void)out_size; (void)ws_size;

  const int N = BH_ * S_ * D_;   // 4,194,304
  unsigned short* qhat = (unsigned short*)d_ws;
  unsigned short* khat = qhat + N;
  unsigned short* vt   = khat + N;
  int*  cnt  = (int*)(vt + N);           // 4 ints (16B-aligned pad)
  float* O1  = (float*)(cnt + 4);        // N floats (chunk-1 partial)
  float2* ml = (float2*)(O1 + N);        // NCH * BH_*S_ float2

  {
    dim3 g(S_ / 64, BH_);
    kvgather_kernel<<<g, 256, 0, stream>>>(k_a, k_s, v_a, v_s, q_a, q_s, mask, cnt,
                                           qhat, khat, vt);
  }
  {
    dim3 g(S_ / QBLK, BH_, NCH);
    attn_kernel<<<g, 256, 0, stream>>>(qhat, khat, vt, cnt, out, O1, ml);
  }
  combine_kernel<<<(BH_ * S_ * 4) / 256, 256, 0, stream>>>(O1, ml, out);
}

// Round 19
// 109.064 us; speedup vs baseline: 1.4600x; 1.0933x over previous
//
#include <hip/hip_runtime.h>
#include <hip/hip_bf16.h>

// (B,H,S,D) = (2,8,4096,64)
#define S_   4096
#define D_   64
#define BH_  16
#define QW   64        // q rows per wave (two 32-col MFMA blocks)
#define QBLK 256       // q rows per block
#define KVB  128       // keys per staged tile (two 64-key halves per barrier)
#define NCH  2         // kv chunks (wave-halves of one block)

typedef __attribute__((ext_vector_type(8)))  short short8_t;   // 8 bf16 (MFMA A/B frag)
typedef __attribute__((ext_vector_type(16))) float f32x16;     // 32x32 MFMA C/D frag
#define QSCALE 0.18033688011112042f   /* (1/8)*log2(e): scores in log2 domain */

__device__ __forceinline__ unsigned short f2bf(float f) {
  unsigned u = __float_as_uint(f);
  u += 0x7fffu + ((u >> 16) & 1u);   // RTNE
  return (unsigned short)(u >> 16);
}

__device__ __forceinline__ void glds16(const unsigned short* g, unsigned short* l) {
  __builtin_amdgcn_global_load_lds(
      (const __attribute__((address_space(1))) unsigned int*)g,
      (__attribute__((address_space(3))) unsigned int*)l, 16, 0, 0);
}

// fused: per-batch mask scan (compact) + K/V gather + Q add/scale convert + V transpose.
__global__ void kvgather_kernel(const float* __restrict__ ka, const float* __restrict__ ks,
                                const float* __restrict__ va, const float* __restrict__ vs,
                                const float* __restrict__ qa, const float* __restrict__ qs,
                                const int* __restrict__ mask, int* __restrict__ cnt,
                                unsigned short* __restrict__ qhat,
                                unsigned short* __restrict__ khat,
                                unsigned short* __restrict__ vt) {
  __shared__ int ps[256];
  __shared__ int srcLds[64];
  __shared__ __align__(16) unsigned short t[D_][72];
  const int bh = blockIdx.y, b = bh >> 3;
  const int s0 = blockIdx.x * 64;
  const int tid = threadIdx.x;

  const int* mb = mask + (size_t)b * S_;
  int m[16], c = 0;
  const int base = tid * 16;
#pragma unroll
  for (int i = 0; i < 16; ++i) { m[i] = mb[base + i]; c += (m[i] != 0); }
  ps[tid] = c;
  __syncthreads();
  for (int off = 1; off < 256; off <<= 1) {   // Hillis-Steele inclusive scan
    int add = (tid >= off) ? ps[tid - off] : 0;
    __syncthreads();
    ps[tid] += add;
    __syncthreads();
  }
  const int C = ps[255];
  int pos = ps[tid] - c;   // exclusive prefix
#pragma unroll
  for (int i = 0; i < 16; ++i) {
    if (m[i]) {
      int r = pos++;
      if (r >= s0 && r < s0 + 64) srcLds[r - s0] = base + i;
    }
  }
  if (tid == 0 && blockIdx.x == 0 && (bh & 7) == 0) cnt[b] = C;
  __syncthreads();

  const int row16 = tid >> 4;
  const int col4  = (tid & 15) * 4;
#pragma unroll
  for (int p = 0; p < 4; ++p) {
    int srow = p * 16 + row16;
    int j = s0 + srow;
    {
      size_t qoff = ((size_t)bh * S_ + j) * D_ + col4;
      float4 xq = *(const float4*)(qa + qoff);
      float4 yq = *(const float4*)(qs + qoff);
      ushort4 rq;
      rq.x = f2bf((xq.x + yq.x) * QSCALE); rq.y = f2bf((xq.y + yq.y) * QSCALE);
      rq.z = f2bf((xq.z + yq.z) * QSCALE); rq.w = f2bf((xq.w + yq.w) * QSCALE);
      *(ushort4*)(qhat + qoff) = rq;
    }
    float4 xv = {0, 0, 0, 0}, yv = {0, 0, 0, 0};
    float4 xk = {0, 0, 0, 0}, yk = {0, 0, 0, 0};
    if (j < C) {
      int src = srcLds[srow];
      size_t off = ((size_t)bh * S_ + src) * D_ + col4;
      xv = *(const float4*)(va + off);
      yv = *(const float4*)(vs + off);
      xk = *(const float4*)(ka + off);
      yk = *(const float4*)(ks + off);
    }
    t[col4 + 0][srow] = f2bf(xv.x + yv.x);
    t[col4 + 1][srow] = f2bf(xv.y + yv.y);
    t[col4 + 2][srow] = f2bf(xv.z + yv.z);
    t[col4 + 3][srow] = f2bf(xv.w + yv.w);
    ushort4 rk;
    rk.x = f2bf(xk.x + yk.x); rk.y = f2bf(xk.y + yk.y);
    rk.z = f2bf(xk.z + yk.z); rk.w = f2bf(xk.w + yk.w);
    *(ushort4*)(khat + ((size_t)bh * S_ + j) * D_ + col4) = rk;
  }
  __syncthreads();
#pragma unroll
  for (int r = 0; r < 2; ++r) {
    int e = (r * 256 + tid) * 8;
    int d = e >> 6, sc = e & 63;
    short8_t v = *(const short8_t*)&t[d][sc];
    *(short8_t*)(vt + ((size_t)bh * D_ + d) * S_ + s0 + sc) = v;
  }
}

// Flash attention, 512 threads = 8 waves: waves 0-3 chunk 0, waves 4-7 chunk 1.
// Per chunk: R18-verified math (swapped QK^T 32x32x16, ones-MFMA row-sum,
// counted-vmcnt double-buffer, two 64-key halves per barrier). In-LDS combine epilogue.
__global__ __launch_bounds__(512, 1) void attn_kernel(
    const unsigned short* __restrict__ Qb, const unsigned short* __restrict__ Kb,
    const unsigned short* __restrict__ Vt, const int* __restrict__ cnt,
    float* __restrict__ out) {
  // 128KB LDS pool: per-chunk K/V double buffers; reused as fp32 partial tile in epilogue
  __shared__ __align__(16) unsigned char smem[131072];
  unsigned short* lKp = (unsigned short*)smem;            // [chunk][buf][8192]
  unsigned short* lVp = lKp + 32768;                      // [chunk][buf][8192]

  const int tid  = threadIdx.x;
  const int wave = tid >> 6;
  const int chid = wave >> 2;          // 0 or 1: KV chunk
  const int wq   = wave & 3;           // q-position wave within chunk
  const int ctid = tid & 255;          // tid within chunk half
  const int lane = tid & 63;
  const int l31  = lane & 31;
  const int h5   = lane >> 5;
  const int rsw  = l31 & 7;
  const int bh   = blockIdx.y;
  const int qrow0 = blockIdx.x * QBLK + wq * QW + l31;   // q-block 0; +32 for q-block 1
  const int b    = bh >> 3;
  const int C    = cnt[b];
  const int NTt  = (C + KVB - 1) / KVB;          // total 128-key tiles
  const int tpc  = (NTt + NCH - 1) / NCH;        // tiles per chunk (uniform loop count)
  const int ts   = chid * tpc;
  const int te   = (ts + tpc < NTt) ? (ts + tpc) : NTt;

  // Q fragments (B-operand)
  short8_t qf[2][4];
#pragma unroll
  for (int qb = 0; qb < 2; ++qb) {
    const unsigned short* qp = Qb + ((size_t)bh * S_ + qrow0 + 32 * qb) * D_ + h5 * 8;
#pragma unroll
    for (int t4 = 0; t4 < 4; ++t4) qf[qb][t4] = *(const short8_t*)(qp + t4 * 16);
  }

  short8_t ones8;
#pragma unroll
  for (int i = 0; i < 8; ++i) ones8[i] = (short)0x3F80;

  const unsigned short* gk0 = Kb + (size_t)bh * S_ * D_;
  const unsigned short* gv0 = Vt + (size_t)bh * D_ * S_;

  // staging geometry (per chunk: 1024 16B-chunks/tile/tensor; 4 per thread of 256)
  int srcK[4], srcV[4], ldsB[4];
#pragma unroll
  for (int r2 = 0; r2 < 4; ++r2) {
    int c = r2 * 256 + ctid;
    int rowK = c >> 3, gK = (c & 7) ^ (rowK & 7);
    srcK[r2] = rowK * 64 + gK * 8;
    int rowV = c >> 4, gg = c & 15;
    int swg = (gg & 8) | ((gg & 7) ^ (rowV & 7));
    srcV[r2] = rowV * S_ + swg * 8;
    ldsB[r2] = r2 * 2048 + wq * 512;   // wave-uniform base within a chunk buffer
  }
  unsigned short* lK0 = lKp + chid * 2 * 8192;   // + buf*8192
  unsigned short* lV0 = lVp + chid * 2 * 8192;

  f32x16 acc0[2], acc1[2], accS[2];
  float mrow[2];
#pragma unroll
  for (int qb = 0; qb < 2; ++qb) {
    acc0[qb] = (f32x16)(0.0f); acc1[qb] = (f32x16)(0.0f); accS[qb] = (f32x16)(0.0f);
    mrow[qb] = -1e30f;
  }

  // prologue: issue tile-ts loads into buf0 (8 per wave); no drain here
  if (ts < te) {
#pragma unroll
    for (int r2 = 0; r2 < 4; ++r2) {
      glds16(gk0 + (size_t)ts * KVB * D_ + srcK[r2], lK0 + ldsB[r2]);
      glds16(gv0 + ts * KVB + srcV[r2], lV0 + ldsB[r2]);
    }
  }

  for (int it = 0; it < tpc; ++it) {     // uniform loop count; barriers unconditional
    const int t = ts + it;
    const int cur = it & 1;
    if (t + 1 < te) {
#pragma unroll
      for (int r2 = 0; r2 < 4; ++r2) {
        glds16(gk0 + (size_t)(t + 1) * KVB * D_ + srcK[r2], lK0 + (cur ^ 1) * 8192 + ldsB[r2]);
        glds16(gv0 + (t + 1) * KVB + srcV[r2], lV0 + (cur ^ 1) * 8192 + ldsB[r2]);
      }
      asm volatile("s_waitcnt vmcnt(8)" ::: "memory");
    } else {
      asm volatile("s_waitcnt vmcnt(0)" ::: "memory");
    }
    __builtin_amdgcn_s_barrier();
    __builtin_amdgcn_sched_barrier(0);

    if (t < te) {
      const unsigned short* lK = lK0 + cur * 8192;
      const unsigned short* lV = lV0 + cur * 8192;
#pragma unroll
      for (int h = 0; h < 2; ++h) {
        f32x16 sv0[2], sv1[2];
#pragma unroll
        for (int qb = 0; qb < 2; ++qb) { sv0[qb] = (f32x16)(0.0f); sv1[qb] = (f32x16)(0.0f); }
        __builtin_amdgcn_s_setprio(1);
#pragma unroll
        for (int t4 = 0; t4 < 4; ++t4) {
          int g = ((2 * t4 + h5) ^ rsw) * 8;
          short8_t kf0 = *(const short8_t*)&lK[(h * 64 + l31) * 64 + g];
          short8_t kf1 = *(const short8_t*)&lK[(h * 64 + 32 + l31) * 64 + g];
          sv0[0] = __builtin_amdgcn_mfma_f32_32x32x16_bf16(kf0, qf[0][t4], sv0[0], 0, 0, 0);
          sv0[1] = __builtin_amdgcn_mfma_f32_32x32x16_bf16(kf0, qf[1][t4], sv0[1], 0, 0, 0);
          sv1[0] = __builtin_amdgcn_mfma_f32_32x32x16_bf16(kf1, qf[0][t4], sv1[0], 0, 0, 0);
          sv1[1] = __builtin_amdgcn_mfma_f32_32x32x16_bf16(kf1, qf[1][t4], sv1[1], 0, 0, 0);
        }
        __builtin_amdgcn_s_setprio(0);

        if (t == NTt - 1) {   // tail: pad keys -> -1e9
          int kvb = t * KVB + h * 64;
#pragma unroll
          for (int i = 0; i < 16; ++i) {
            int key = kvb + (i & 3) + 8 * (i >> 2) + 4 * h5;
#pragma unroll
            for (int qb = 0; qb < 2; ++qb) {
              if (key >= C) sv0[qb][i] = -1e9f;
              if (key + 32 >= C) sv1[qb][i] = -1e9f;
            }
          }
        }

        unsigned int pkw[2][16];
#pragma unroll
        for (int qb = 0; qb < 2; ++qb) {
          float tmx[8];
#pragma unroll
          for (int i = 0; i < 8; ++i)
            tmx[i] = fmaxf(fmaxf(sv0[qb][i], sv0[qb][i + 8]),
                           fmaxf(sv1[qb][i], sv1[qb][i + 8]));
#pragma unroll
          for (int i = 0; i < 4; ++i) tmx[i] = fmaxf(tmx[i], tmx[i + 4]);
          float tm = fmaxf(fmaxf(tmx[0], tmx[1]), fmaxf(tmx[2], tmx[3]));
          tm = fmaxf(tm, __shfl_xor(tm, 32));

          if (__any(tm > mrow[qb] + 8.0f)) {   // defer-max (T13)
            float mnew = fmaxf(mrow[qb], tm);
            float sc = __builtin_amdgcn_exp2f(mrow[qb] - mnew);
            mrow[qb] = mnew;
            accS[qb][0] *= sc;
#pragma unroll
            for (int i = 0; i < 16; ++i) { acc0[qb][i] *= sc; acc1[qb][i] *= sc; }
          }

          float m = mrow[qb];
#pragma unroll
          for (int i = 0; i < 16; i += 4) {
            sv0[qb][i + 0] = __builtin_amdgcn_exp2f(sv0[qb][i + 0] - m);
            sv0[qb][i + 1] = __builtin_amdgcn_exp2f(sv0[qb][i + 1] - m);
            sv0[qb][i + 2] = __builtin_amdgcn_exp2f(sv0[qb][i + 2] - m);
            sv0[qb][i + 3] = __builtin_amdgcn_exp2f(sv0[qb][i + 3] - m);
            sv1[qb][i + 0] = __builtin_amdgcn_exp2f(sv1[qb][i + 0] - m);
            sv1[qb][i + 1] = __builtin_amdgcn_exp2f(sv1[qb][i + 1] - m);
            sv1[qb][i + 2] = __builtin_amdgcn_exp2f(sv1[qb][i + 2] - m);
            sv1[qb][i + 3] = __builtin_amdgcn_exp2f(sv1[qb][i + 3] - m);
          }

#pragma unroll
          for (int rg = 0; rg < 4; ++rg) {
            __hip_bfloat162 a0 = __float22bfloat162_rn({sv0[qb][rg * 4 + 0], sv0[qb][rg * 4 + 1]});
            __hip_bfloat162 a1 = __float22bfloat162_rn({sv0[qb][rg * 4 + 2], sv0[qb][rg * 4 + 3]});
            __hip_bfloat162 b0 = __float22bfloat162_rn({sv1[qb][rg * 4 + 0], sv1[qb][rg * 4 + 1]});
            __hip_bfloat162 b1 = __float22bfloat162_rn({sv1[qb][rg * 4 + 2], sv1[qb][rg * 4 + 3]});
            pkw[qb][rg * 2 + 0] = *(unsigned int*)&a0;
            pkw[qb][rg * 2 + 1] = *(unsigned int*)&a1;
            pkw[qb][8 + rg * 2 + 0] = *(unsigned int*)&b0;
            pkw[qb][8 + rg * 2 + 1] = *(unsigned int*)&b1;
          }
        }

        // O^T += V^T P (+ row-sum ones-MFMA); shfl redistribution (R4-verified)
        __builtin_amdgcn_s_setprio(1);
#pragma unroll
        for (int kt = 0; kt < 4; ++kt) {
          const int n = kt >> 1, k1 = kt & 1;
          int gcol = ((h * 8) | ((2 * kt + h5) ^ rsw)) * 8;
          short8_t vf0 = *(const short8_t*)&lV[l31 * KVB + gcol];
          short8_t vf1 = *(const short8_t*)&lV[(32 + l31) * KVB + gcol];
#pragma unroll
          for (int qb = 0; qb < 2; ++qb) {
            unsigned int sA = pkw[qb][n * 8 + (2 * k1 + h5) * 2 + 0];
            unsigned int sB = pkw[qb][n * 8 + (2 * k1 + h5) * 2 + 1];
            unsigned int xA = pkw[qb][n * 8 + (2 * k1 + (h5 ^ 1)) * 2 + 0];
            unsigned int xB = pkw[qb][n * 8 + (2 * k1 + (h5 ^ 1)) * 2 + 1];
            unsigned int pA = (unsigned int)__shfl_xor((int)xA, 32);
            unsigned int pB = (unsigned int)__shfl_xor((int)xB, 32);
            union { unsigned int u[4]; short8_t v; } bb;
            bb.u[0] = h5 ? pA : sA;
            bb.u[1] = h5 ? pB : sB;
            bb.u[2] = h5 ? sA : pA;
            bb.u[3] = h5 ? sB : pB;
            acc0[qb] = __builtin_amdgcn_mfma_f32_32x32x16_bf16(vf0, bb.v, acc0[qb], 0, 0, 0);
            acc1[qb] = __builtin_amdgcn_mfma_f32_32x32x16_bf16(vf1, bb.v, acc1[qb], 0, 0, 0);
            accS[qb] = __builtin_amdgcn_mfma_f32_32x32x16_bf16(ones8, bb.v, accS[qb], 0, 0, 0);
          }
        }
        __builtin_amdgcn_s_setprio(0);
      }
    }

    __builtin_amdgcn_sched_barrier(0);
    __builtin_amdgcn_s_barrier();   // all waves done with buf[cur] before next glds
  }

  // ---- in-LDS combine: chunk 1 publishes partials, chunk 0 merges + writes out
  float* part = (float*)smem;                 // [256 rows][72] fp32 (aligned float4 rows)
  float2* mlsh = (float2*)(smem + 73728);     // [256] (m, l)
  __syncthreads();                            // staging LDS dead; safe to overwrite

  if (chid == 1) {
#pragma unroll
    for (int qb = 0; qb < 2; ++qb) {
      int rl = wq * 64 + qb * 32 + l31;
      float* pr = part + rl * 72;
#pragma unroll
      for (int rg = 0; rg < 4; ++rg) {
        float4 o0, o1;
        o0.x = acc0[qb][rg * 4 + 0]; o0.y = acc0[qb][rg * 4 + 1];
        o0.z = acc0[qb][rg * 4 + 2]; o0.w = acc0[qb][rg * 4 + 3];
        o1.x = acc1[qb][rg * 4 + 0]; o1.y = acc1[qb][rg * 4 + 1];
        o1.z = acc1[qb][rg * 4 + 2]; o1.w = acc1[qb][rg * 4 + 3];
        *(float4*)(pr + rg * 8 + h5 * 4) = o0;
        *(float4*)(pr + 32 + rg * 8 + h5 * 4) = o1;
      }
      if (h5 == 0) { float2 st; st.x = mrow[qb]; st.y = accS[qb][0]; mlsh[rl] = st; }
    }
  }
  __syncthreads();
  if (chid == 0) {
#pragma unroll
    for (int qb = 0; qb < 2; ++qb) {
      int rl = wq * 64 + qb * 32 + l31;
      float2 pml = mlsh[rl];
      float m0 = mrow[qb], l0 = accS[qb][0];
      float M = fmaxf(m0, pml.x);
      float w0 = exp2f(m0 - M), w1 = exp2f(pml.x - M);
      float inv = 1.0f / (l0 * w0 + pml.y * w1);
      w0 *= inv; w1 *= inv;
      const float* pr = part + rl * 72;
      float* op = out + ((size_t)bh * S_ + qrow0 + 32 * qb) * D_;
#pragma unroll
      for (int rg = 0; rg < 4; ++rg) {
        float4 p0v = *(const float4*)(pr + rg * 8 + h5 * 4);
        float4 p1v = *(const float4*)(pr + 32 + rg * 8 + h5 * 4);
        float4 o0, o1;
        o0.x = acc0[qb][rg * 4 + 0] * w0 + p0v.x * w1;
        o0.y = acc0[qb][rg * 4 + 1] * w0 + p0v.y * w1;
        o0.z = acc0[qb][rg * 4 + 2] * w0 + p0v.z * w1;
        o0.w = acc0[qb][rg * 4 + 3] * w0 + p0v.w * w1;
        o1.x = acc1[qb][rg * 4 + 0] * w0 + p1v.x * w1;
        o1.y = acc1[qb][rg * 4 + 1] * w0 + p1v.y * w1;
        o1.z = acc1[qb][rg * 4 + 2] * w0 + p1v.z * w1;
        o1.w = acc1[qb][rg * 4 + 3] * w0 + p1v.w * w1;
        *(float4*)(op + rg * 8 + h5 * 4) = o0;
        *(float4*)(op + 32 + rg * 8 + h5 * 4) = o1;
      }
    }
  }
}

extern "C" void kernel_launch(void* const* d_in, const int* in_sizes, int n_in,
                              void* d_out, int out_size, void* d_ws, size_t ws_size,
                              hipStream_t stream) {
  const float* q_a = (const float*)d_in[0];
  const float* k_a = (const float*)d_in[1];
  const float* v_a = (const float*)d_in[2];
  const float* q_s = (const float*)d_in[3];
  const float* k_s = (const float*)d_in[4];
  const float* v_s = (const float*)d_in[5];
  const int*   mask = (const int*)d_in[6];
  float* out = (float*)d_out;
  (void)in_sizes; (void)n_in; (void)out_size; (void)ws_size;

  const int N = BH_ * S_ * D_;   // 4,194,304
  unsigned short* qhat = (unsigned short*)d_ws;
  unsigned short* khat = qhat + N;
  unsigned short* vt   = khat + N;
  int* cnt = (int*)(vt + N);             // 4 ints

  {
    dim3 g(S_ / 64, BH_);
    kvgather_kernel<<<g, 256, 0, stream>>>(k_a, k_s, v_a, v_s, q_a, q_s, mask, cnt,
                                           qhat, khat, vt);
  }
  {
    dim3 g(S_ / QBLK, BH_);
    attn_kernel<<<g, 512, 0, stream>>>(qhat, khat, vt, cnt, out);
  }
}